// Round 10
// baseline (1464.031 us; speedup 1.0000x reference)
//
#include <hip/hip_runtime.h>

typedef _Float16 f16;
typedef _Float16 f16x8 __attribute__((ext_vector_type(8)));
typedef _Float16 f16x4 __attribute__((ext_vector_type(4)));
typedef float    f32x4 __attribute__((ext_vector_type(4)));
typedef unsigned long long ull;

static constexpr int Bb  = 32;
static constexpr int Tt  = 128;
static constexpr int HID = 1024;
static constexpr int ZD  = 256;
static constexpr int DE  = 512;
static constexpr int VOC = 32000;
static constexpr int BT  = Bb * Tt;   // 4096
static constexpr int G4  = 4 * HID;   // 4096
static constexpr int NB  = 64;        // lstm blocks (16 hidden units each)
// HS2 slot layout: slot s in [0,128], chunk blk in [0,64), [b][u] inside:
//   half index = s*32768 + blk*512 + b*16 + u.  Slot s holds h_{s-1} (h0 in slot 0).
// Slots 1..128 are poisoned to 0xFFFF (f16 NaN) each call: DATA IS THE FLAG.

// ---- async global->LDS, 16B per lane; LDS dest = wave-uniform base + lane*16 ----
__device__ __forceinline__ void gld_lds16(const void* g, void* l) {
  __builtin_amdgcn_global_load_lds((const __attribute__((address_space(1))) unsigned int*)g,
                                   (__attribute__((address_space(3))) unsigned int*)l,
                                   16, 0, 0);
}

// true iff no 16-bit half of v equals 0xFFFF (the sentinel)
__device__ __forceinline__ bool valid8(ull v) {
  ull x = ~v;  // sentinel half -> 0x0000
  return ((x - 0x0001000100010001ull) & ~x & 0x8000800080008000ull) == 0;
}

// ---------------- f32 -> f16 convert (vectorized) ----------------
__global__ void cvt_kernel(const float* __restrict__ s, f16* __restrict__ d, int n4) {
  int i = blockIdx.x * blockDim.x + threadIdx.x;
  int st = gridDim.x * blockDim.x;
  for (; i < n4; i += st) {
    float4 v = ((const float4*)s)[i];
    f16x4 o = { (f16)v.x, (f16)v.y, (f16)v.z, (f16)v.w };
    ((f16x4*)d)[i] = o;
  }
}

// ---------------- embedding gather -> f16 ----------------
__global__ void gather_kernel(const float* __restrict__ emb, const int* __restrict__ x,
                              f16* __restrict__ E) {
  int g = blockIdx.x * 256 + threadIdx.x;   // BT*DE/8 threads
  int m = g >> 6, seg = (g & 63) * 8;
  int idx = x[m];
  const float* src = emb + (size_t)idx * DE + seg;
  float4 a = *(const float4*)src;
  float4 b = *(const float4*)(src + 4);
  f16x8 o = { (f16)a.x,(f16)a.y,(f16)a.z,(f16)a.w,(f16)b.x,(f16)b.y,(f16)b.z,(f16)b.w };
  *(f16x8*)(E + (size_t)m * DE + seg) = o;
}

// ---------------- bias sum ----------------
__global__ void bsum_kernel(const float* __restrict__ a, const float* __restrict__ b,
                            float* __restrict__ o, int n) {
  int i = blockIdx.x * blockDim.x + threadIdx.x;
  if (i < n) o[i] = a[i] + b[i];
}

// ---------------- h0 = tanh(z @ W_h^T + b_h) -> HS2 slot 0 (chunk layout) --------
__global__ __launch_bounds__(256) void h0_kernel(const float* __restrict__ z,
                                                 const float* __restrict__ W_h,
                                                 const float* __restrict__ b_h,
                                                 f16* __restrict__ h0c) {
  __shared__ float zs[32][260];
  __shared__ float wsl[8][260];
  const int jc = blockIdx.x, tid = threadIdx.x;
  #pragma unroll
  for (int it = 0; it < 8; ++it) {
    int idx = it * 256 + tid;
    float4 v = ((const float4*)z)[idx];
    int b = idx >> 6, k = (idx & 63) * 4;
    zs[b][k] = v.x; zs[b][k+1] = v.y; zs[b][k+2] = v.z; zs[b][k+3] = v.w;
  }
  #pragma unroll
  for (int it = 0; it < 2; ++it) {
    int idx = it * 256 + tid;
    float4 v = ((const float4*)(W_h + (size_t)jc * 8 * ZD))[idx];
    int r = idx >> 6, k = (idx & 63) * 4;
    wsl[r][k] = v.x; wsl[r][k+1] = v.y; wsl[r][k+2] = v.z; wsl[r][k+3] = v.w;
  }
  __syncthreads();
  const int b = tid >> 3, jj = tid & 7;
  const int j = jc * 8 + jj;
  float acc = b_h[j];
  for (int k = 0; k < ZD; ++k) acc += zs[b][k] * wsl[jj][k];
  h0c[(size_t)(j >> 4) * 512 + b * 16 + (j & 15)] = (f16)tanhf(acc);
}

// ---------------- GEMM: C = A[M,K] @ B[N,K]^T + bias[N]  (f16 in, f32 out) --------
// XGOUT: C laid out [g][b][t] float (for the x-gate GEMM).
// AHS2 : A is the LSTM h-state in slot/chunk layout; A[m][k] (m=b*128+t, k=j) at
//        half-index ((m&127)+1)*32768 + (k>>4)*512 + (m>>7)*16 + (k&15).
template <bool XGOUT, bool AHS2>
__global__ __launch_bounds__(256, 2) void gemm_kernel(
    const f16* __restrict__ A, const f16* __restrict__ B,
    const float* __restrict__ bias, float* __restrict__ C,
    int M, int N, int K) {
  __shared__ f16 As[128 * 64];
  __shared__ f16 Bs[128 * 64];
  const int n0 = blockIdx.x * 128, m0 = blockIdx.y * 128;
  const int tid = threadIdx.x, wid = tid >> 6, lane = tid & 63;
  const int wm = wid >> 1, wn = wid & 1;
  const int sr = lane >> 3, sk = (lane & 7) * 8;
  f32x4 acc[4][4] = {};
  for (int k0 = 0; k0 < K; k0 += 64) {
    __syncthreads();
    #pragma unroll
    for (int i = 0; i < 4; ++i) {
      int rr = (wid * 4 + i) * 8;
      const f16* asrc;
      if (AHS2) {
        int m = m0 + rr + sr, k = k0 + sk;
        asrc = A + (size_t)((m & 127) + 1) * 32768 + (size_t)(k >> 4) * 512
                 + (m >> 7) * 16 + (k & 15);
      } else {
        asrc = A + (size_t)(m0 + rr + sr) * K + k0 + sk;
      }
      gld_lds16(asrc, &As[rr * 64]);
      gld_lds16(B + (size_t)(n0 + rr + sr) * K + k0 + sk, &Bs[rr * 64]);
    }
    __syncthreads();
    #pragma unroll
    for (int ks = 0; ks < 2; ++ks) {
      f16x8 af[4], bf[4];
      #pragma unroll
      for (int mt = 0; mt < 4; ++mt)
        af[mt] = *(const f16x8*)&As[(wm * 64 + mt * 16 + (lane & 15)) * 64 + ks * 32 + (lane >> 4) * 8];
      #pragma unroll
      for (int nt = 0; nt < 4; ++nt)
        bf[nt] = *(const f16x8*)&Bs[(wn * 64 + nt * 16 + (lane & 15)) * 64 + ks * 32 + (lane >> 4) * 8];
      #pragma unroll
      for (int mt = 0; mt < 4; ++mt)
        #pragma unroll
        for (int nt = 0; nt < 4; ++nt)
          acc[mt][nt] = __builtin_amdgcn_mfma_f32_16x16x32_f16(af[mt], bf[nt], acc[mt][nt], 0, 0, 0);
    }
  }
  #pragma unroll
  for (int nt = 0; nt < 4; ++nt) {
    int col = n0 + wn * 64 + nt * 16 + (lane & 15);
    float bv = bias[col];
    #pragma unroll
    for (int mt = 0; mt < 4; ++mt) {
      int row = m0 + wm * 64 + mt * 16 + (lane >> 4) * 4;
      if (XGOUT) {
        int b = row >> 7, t0 = row & 127;
        float4 v = { acc[mt][nt][0] + bv, acc[mt][nt][1] + bv,
                     acc[mt][nt][2] + bv, acc[mt][nt][3] + bv };
        *(float4*)&C[((size_t)col * 32 + b) * 128 + t0] = v;
      } else {
        #pragma unroll
        for (int p = 0; p < 4; ++p)
          C[(size_t)(row + p) * N + col] = acc[mt][nt][p] + bv;
      }
    }
  }
}

// ---------------- persistent LSTM recurrence (v9: data-as-flag, parallel retry) --
// 64 blocks x 512 threads (8 waves). Block bid owns 16 hidden units (64 gate rows),
// W_hh fragments in VGPRs (wave wid owns k-range wid*128..+128).
// No flags/fences/drains: HS2 slots pre-poisoned to 0xFFFF (f16 NaN, unreachable by
// h = og*tanh(c)); producers store h per-thread (relaxed agent 2B); consumers issue
// ALL 16 probe loads of their 8 chunks in one batch (one vmcnt wait), sentinel-check
// all halves, and re-issue the whole batch only while any half is missing.
__global__ __launch_bounds__(512, 1) void lstm_kernel(
    const f16* __restrict__ Whh16,   // [4096][1024]
    const float* __restrict__ XG2,   // [g][b][t] : ((g*32)+b)*128+t
    f16* __restrict__ HS2) {         // slot/chunk layout, slots 0..128
  const int bid = blockIdx.x, tid = threadIdx.x;
  const int lane = tid & 63, wid = tid >> 6;
  const int lr = lane & 15, hi = lane >> 4;
  const int j0 = bid * 16;
  __shared__ __align__(16) f16 hl2[64][512];       // h_{t-1} chunks [blk][b*16+u]
  __shared__ float part[8][64][33];                // per-wave K-partials

  // preload W fragments (once): wave wid covers k in [wid*128, wid*128+128)
  f16x8 wfrag[4][4];
  #pragma unroll
  for (int rt = 0; rt < 4; ++rt) {                 // rt = gate q; unit row = lr
    int g = rt * HID + j0 + lr;
    #pragma unroll
    for (int kk = 0; kk < 4; ++kk)
      wfrag[rt][kk] = *(const f16x8*)(Whh16 + (size_t)g * HID + wid * 128 + kk * 32 + hi * 8);
  }

  const int ub = tid & 15, bb = tid >> 4;          // thread owns (unit ub, batch bb)
  float creg = 0.f;

  for (int t = 0; t < Tt; ++t) {
    // ---- XG prefetch (plain cached loads; 128B line serves 32 steps from L2) ----
    float xg[4];
    #pragma unroll
    for (int q = 0; q < 4; ++q)
      xg[q] = XG2[((size_t)(q * HID + j0 + ub) * 32 + bb) * 128 + t];

    // ---- stage slot t: batch-probe all 8 chunks, parallel sentinel retry ----
    {
      const f16* slot = HS2 + (size_t)t * 32768;
      ull a0[8], a1[8];
      #pragma unroll
      for (int c = 0; c < 8; ++c) {
        const ull* src = (const ull*)(slot + (wid * 8 + c) * 512);
        a0[c] = __hip_atomic_load(src + lane * 2,     __ATOMIC_RELAXED, __HIP_MEMORY_SCOPE_AGENT);
        a1[c] = __hip_atomic_load(src + lane * 2 + 1, __ATOMIC_RELAXED, __HIP_MEMORY_SCOPE_AGENT);
      }
      for (;;) {
        bool ok = true;
        #pragma unroll
        for (int c = 0; c < 8; ++c) ok = ok && valid8(a0[c]) && valid8(a1[c]);
        if (__all(ok)) break;
        #pragma unroll
        for (int c = 0; c < 8; ++c) {
          const ull* src = (const ull*)(slot + (wid * 8 + c) * 512);
          a0[c] = __hip_atomic_load(src + lane * 2,     __ATOMIC_RELAXED, __HIP_MEMORY_SCOPE_AGENT);
          a1[c] = __hip_atomic_load(src + lane * 2 + 1, __ATOMIC_RELAXED, __HIP_MEMORY_SCOPE_AGENT);
        }
      }
      #pragma unroll
      for (int c = 0; c < 8; ++c) {
        int blk = wid * 8 + c;
        *(ull*)&hl2[blk][lane * 8]     = a0[c];
        *(ull*)&hl2[blk][lane * 8 + 4] = a1[c];
      }
    }
    __syncthreads();   // hl2 complete (also: all waves done reading part of t-1)

    // ---- gate MFMA: C[64 gate rows][32 batches], this wave's k-eighth ----
    {
      f32x4 acc[4][2] = {};
      #pragma unroll
      for (int kk = 0; kk < 4; ++kk) {
        int ko = wid * 128 + kk * 32 + hi * 8;
        int c = ko >> 4, uo = ko & 15;
        f16x8 bf0 = *(const f16x8*)&hl2[c][lr * 16 + uo];
        f16x8 bf1 = *(const f16x8*)&hl2[c][(16 + lr) * 16 + uo];
        #pragma unroll
        for (int rt = 0; rt < 4; ++rt) {
          acc[rt][0] = __builtin_amdgcn_mfma_f32_16x16x32_f16(wfrag[rt][kk], bf0, acc[rt][0], 0, 0, 0);
          acc[rt][1] = __builtin_amdgcn_mfma_f32_16x16x32_f16(wfrag[rt][kk], bf1, acc[rt][1], 0, 0, 0);
        }
      }
      #pragma unroll
      for (int rt = 0; rt < 4; ++rt)
        #pragma unroll
        for (int bt = 0; bt < 2; ++bt)
          #pragma unroll
          for (int p = 0; p < 4; ++p)
            part[wid][rt * 16 + hi * 4 + p][bt * 16 + lr] = acc[rt][bt][p];
    }
    __syncthreads();   // part complete

    // ---- LSTM update: thread (ub, bb); h_t store IS the ready signal ----
    {
      float g4[4];
      #pragma unroll
      for (int q = 0; q < 4; ++q) {
        int i = q * 16 + ub;
        float s = xg[q];
        #pragma unroll
        for (int w = 0; w < 8; ++w) s += part[w][i][bb];
        g4[q] = s;
      }
      float ig = 1.f / (1.f + __expf(-g4[0]));
      float fg = 1.f / (1.f + __expf(-g4[1]));
      float gg = tanhf(g4[2]);
      float og = 1.f / (1.f + __expf(-g4[3]));
      creg = fg * creg + ig * gg;
      float h = og * tanhf(creg);
      union { f16 h; unsigned short u; } cv;
      cv.h = (f16)h;
      __hip_atomic_store((unsigned short*)(HS2 + (size_t)(t + 1) * 32768 + bid * 512 + tid),
                         cv.u, __ATOMIC_RELAXED, __HIP_MEMORY_SCOPE_AGENT);
    }
    // no drain / no flag: consumers detect the data itself
  }
}

extern "C" void kernel_launch(void* const* d_in, const int* in_sizes, int n_in,
                              void* d_out, int out_size, void* d_ws, size_t ws_size,
                              hipStream_t stream) {
  const float* z     = (const float*)d_in[0];
  const int*   x     = (const int*)d_in[1];
  const float* W_h   = (const float*)d_in[2];
  const float* b_h   = (const float*)d_in[3];
  const float* emb   = (const float*)d_in[4];
  const float* W_ih  = (const float*)d_in[5];
  const float* W_hh  = (const float*)d_in[6];
  const float* b_ih  = (const float*)d_in[7];
  const float* b_hh  = (const float*)d_in[8];
  const float* W_out = (const float*)d_in[9];
  const float* b_out = (const float*)d_in[10];
  float* out = (float*)d_out;

  char* ws = (char*)d_ws;
  size_t off = 0;
  auto carve = [&](size_t n) { char* p = ws + off; off += (n + 255) & ~(size_t)255; return p; };
  f16*   E16    = (f16*)carve((size_t)BT * DE * 2);       // 4 MB
  f16*   Wih16  = (f16*)carve((size_t)G4 * DE * 2);       // 4 MB
  f16*   Whh16  = (f16*)carve((size_t)G4 * HID * 2);      // 8 MB
  f16*   Wout16 = (f16*)carve((size_t)VOC * HID * 2);     // 64 MB
  float* XG2    = (float*)carve((size_t)BT * G4 * 4);     // 64 MB, [g][b][t]
  f16*   HS2    = (f16*)carve((size_t)129 * 64 * 512 * 2);// 8.4 MB, slots 0..128
  float* bs     = (float*)carve((size_t)G4 * 4);

  // poison h slots 1..128 with 0xFFFF sentinel (data-as-flag), every call
  (void)hipMemsetAsync(HS2 + 32768, 0xFF, (size_t)128 * 32768 * 2, stream);

  cvt_kernel<<<2048, 256, 0, stream>>>(W_ih,  Wih16,  G4 * DE / 4);
  cvt_kernel<<<2048, 256, 0, stream>>>(W_hh,  Whh16,  G4 * HID / 4);
  cvt_kernel<<<2048, 256, 0, stream>>>(W_out, Wout16, VOC * HID / 4);
  gather_kernel<<<BT * DE / 8 / 256, 256, 0, stream>>>(emb, x, E16);
  bsum_kernel<<<16, 256, 0, stream>>>(b_ih, b_hh, bs, G4);
  h0_kernel<<<128, 256, 0, stream>>>(z, W_h, b_h, HS2);   // writes slot 0

  dim3 g1(G4 / 128, BT / 128);     // 32 x 32
  gemm_kernel<true, false><<<g1, 256, 0, stream>>>(E16, Wih16, bs, XG2, BT, G4, DE);

  lstm_kernel<<<NB, 512, 0, stream>>>(Whh16, XG2, HS2);

  dim3 g2(VOC / 128, BT / 128);    // 250 x 32
  gemm_kernel<false, true><<<g2, 256, 0, stream>>>(HS2, Wout16, b_out, out, BT, VOC, HID);
}

// Round 11
// 1103.544 us; speedup vs baseline: 1.3267x; 1.3267x over previous
//
#include <hip/hip_runtime.h>

typedef _Float16 f16;
typedef _Float16 f16x8 __attribute__((ext_vector_type(8)));
typedef _Float16 f16x4 __attribute__((ext_vector_type(4)));
typedef float    f32x4 __attribute__((ext_vector_type(4)));
typedef unsigned long long ull;

static constexpr int Bb  = 32;
static constexpr int Tt  = 128;
static constexpr int HID = 1024;
static constexpr int ZD  = 256;
static constexpr int DE  = 512;
static constexpr int VOC = 32000;
static constexpr int BT  = Bb * Tt;   // 4096
static constexpr int G4  = 4 * HID;   // 4096
static constexpr int NB  = 64;        // lstm blocks (16 hidden units each)

// ---- async global->LDS, 16B per lane; LDS dest = wave-uniform base + lane*16 ----
__device__ __forceinline__ void gld_lds16(const void* g, void* l) {
  __builtin_amdgcn_global_load_lds((const __attribute__((address_space(1))) unsigned int*)g,
                                   (__attribute__((address_space(3))) unsigned int*)l,
                                   16, 0, 0);
}

// ---------------- f32 -> f16 convert (vectorized) ----------------
__global__ void cvt_kernel(const float* __restrict__ s, f16* __restrict__ d, int n4) {
  int i = blockIdx.x * blockDim.x + threadIdx.x;
  int st = gridDim.x * blockDim.x;
  for (; i < n4; i += st) {
    float4 v = ((const float4*)s)[i];
    f16x4 o = { (f16)v.x, (f16)v.y, (f16)v.z, (f16)v.w };
    ((f16x4*)d)[i] = o;
  }
}

// ---------------- embedding gather -> f16 ----------------
__global__ void gather_kernel(const float* __restrict__ emb, const int* __restrict__ x,
                              f16* __restrict__ E) {
  int g = blockIdx.x * 256 + threadIdx.x;   // BT*DE/8 threads
  int m = g >> 6, seg = (g & 63) * 8;
  int idx = x[m];
  const float* src = emb + (size_t)idx * DE + seg;
  float4 a = *(const float4*)src;
  float4 b = *(const float4*)(src + 4);
  f16x8 o = { (f16)a.x,(f16)a.y,(f16)a.z,(f16)a.w,(f16)b.x,(f16)b.y,(f16)b.z,(f16)b.w };
  *(f16x8*)(E + (size_t)m * DE + seg) = o;
}

// ---------------- bias sum ----------------
__global__ void bsum_kernel(const float* __restrict__ a, const float* __restrict__ b,
                            float* __restrict__ o, int n) {
  int i = blockIdx.x * blockDim.x + threadIdx.x;
  if (i < n) o[i] = a[i] + b[i];
}

// ---------------- h0 = tanh(z @ W_h^T + b_h), store f16 ----------------
__global__ __launch_bounds__(256) void h0_kernel(const float* __restrict__ z,
                                                 const float* __restrict__ W_h,
                                                 const float* __restrict__ b_h,
                                                 f16* __restrict__ h0f) {
  __shared__ float zs[32][260];
  __shared__ float wsl[8][260];
  const int jc = blockIdx.x, tid = threadIdx.x;
  #pragma unroll
  for (int it = 0; it < 8; ++it) {
    int idx = it * 256 + tid;
    float4 v = ((const float4*)z)[idx];
    int b = idx >> 6, k = (idx & 63) * 4;
    zs[b][k] = v.x; zs[b][k+1] = v.y; zs[b][k+2] = v.z; zs[b][k+3] = v.w;
  }
  #pragma unroll
  for (int it = 0; it < 2; ++it) {
    int idx = it * 256 + tid;
    float4 v = ((const float4*)(W_h + (size_t)jc * 8 * ZD))[idx];
    int r = idx >> 6, k = (idx & 63) * 4;
    wsl[r][k] = v.x; wsl[r][k+1] = v.y; wsl[r][k+2] = v.z; wsl[r][k+3] = v.w;
  }
  __syncthreads();
  const int b = tid >> 3, jj = tid & 7;
  const int j = jc * 8 + jj;
  float acc = b_h[j];
  for (int k = 0; k < ZD; ++k) acc += zs[b][k] * wsl[jj][k];
  h0f[(size_t)b * HID + j] = (f16)tanhf(acc);
}

// ---------------- GEMM 128x128 (proven): C = A @ B^T + bias, XGOUT variant ------
template <bool XGOUT>
__global__ __launch_bounds__(256, 2) void gemm_kernel(
    const f16* __restrict__ A, const f16* __restrict__ B,
    const float* __restrict__ bias, float* __restrict__ C,
    int M, int N, int K) {
  __shared__ f16 As[128 * 64];
  __shared__ f16 Bs[128 * 64];
  const int n0 = blockIdx.x * 128, m0 = blockIdx.y * 128;
  const int tid = threadIdx.x, wid = tid >> 6, lane = tid & 63;
  const int wm = wid >> 1, wn = wid & 1;
  const int sr = lane >> 3, sk = (lane & 7) * 8;
  f32x4 acc[4][4] = {};
  for (int k0 = 0; k0 < K; k0 += 64) {
    __syncthreads();
    #pragma unroll
    for (int i = 0; i < 4; ++i) {
      int rr = (wid * 4 + i) * 8;
      gld_lds16(A + (size_t)(m0 + rr + sr) * K + k0 + sk, &As[rr * 64]);
      gld_lds16(B + (size_t)(n0 + rr + sr) * K + k0 + sk, &Bs[rr * 64]);
    }
    __syncthreads();
    #pragma unroll
    for (int ks = 0; ks < 2; ++ks) {
      f16x8 af[4], bf[4];
      #pragma unroll
      for (int mt = 0; mt < 4; ++mt)
        af[mt] = *(const f16x8*)&As[(wm * 64 + mt * 16 + (lane & 15)) * 64 + ks * 32 + (lane >> 4) * 8];
      #pragma unroll
      for (int nt = 0; nt < 4; ++nt)
        bf[nt] = *(const f16x8*)&Bs[(wn * 64 + nt * 16 + (lane & 15)) * 64 + ks * 32 + (lane >> 4) * 8];
      #pragma unroll
      for (int mt = 0; mt < 4; ++mt)
        #pragma unroll
        for (int nt = 0; nt < 4; ++nt)
          acc[mt][nt] = __builtin_amdgcn_mfma_f32_16x16x32_f16(af[mt], bf[nt], acc[mt][nt], 0, 0, 0);
    }
  }
  #pragma unroll
  for (int nt = 0; nt < 4; ++nt) {
    int col = n0 + wn * 64 + nt * 16 + (lane & 15);
    float bv = bias[col];
    #pragma unroll
    for (int mt = 0; mt < 4; ++mt) {
      int row = m0 + wm * 64 + mt * 16 + (lane >> 4) * 4;
      if (XGOUT) {
        int b = row >> 7, t0 = row & 127;
        float4 v = { acc[mt][nt][0] + bv, acc[mt][nt][1] + bv,
                     acc[mt][nt][2] + bv, acc[mt][nt][3] + bv };
        *(float4*)&C[((size_t)col * 32 + b) * 128 + t0] = v;
      } else {
        #pragma unroll
        for (int p = 0; p < 4; ++p)
          C[(size_t)(row + p) * N + col] = acc[mt][nt][p] + bv;
      }
    }
  }
}

// ---------------- GEMM 256x256, BK=32, 4-buf ring, counted vmcnt (T3+T4+T5) ------
// 512 threads = 8 waves (2M x 4N); per-wave output 128x64 (8x4 16x16 frags).
// Ring of 4 LDS buffers, prefetch depth 3: iter kt = vmcnt(8) [counted, never 0
// mid-loop] -> raw s_barrier (no implicit drain) -> STAGE(kt+3) -> ds_read ->
// setprio(1) + 32 MFMA + setprio(0). vmcnt(8): <=12 outstanding (kt,kt+1,kt+2
// stages x 4 loads) -> kt's landed. Barrier at kt proves all waves consumed
// buf[(kt-1)&3], so STAGE(kt+3) into that buf is safe.
__global__ __launch_bounds__(512, 2) void gemm256_kernel(
    const f16* __restrict__ A,   // [M][K]
    const f16* __restrict__ B,   // [N][K]
    const float* __restrict__ bias, float* __restrict__ C,
    int M, int N, int K) {
  __shared__ __align__(16) f16 As[4][256 * 32];
  __shared__ __align__(16) f16 Bs[4][256 * 32];
  const int n0 = blockIdx.x * 256, m0 = blockIdx.y * 256;
  const int tid = threadIdx.x, wid = tid >> 6, lane = tid & 63;
  const int wm = wid >> 2, wn = wid & 3;
  const int lr = lane & 15, hi = lane >> 4;
  const int srow = lane >> 2, scol = (lane & 3) * 8;   // staging: 16 rows x 64B
  const int NT = K >> 5;                                // BK=32

  f32x4 acc[8][4] = {};

  auto STAGE = [&](int kt) {
    const int k0 = kt << 5, buf = kt & 3;
    #pragma unroll
    for (int i = 0; i < 2; ++i) {
      int cb = wid * 2 + i;                             // 0..15, 16-row group
      int row = cb * 16 + srow;
      gld_lds16(A + (size_t)(m0 + row) * K + k0 + scol, &As[buf][cb * 512]);
      gld_lds16(B + (size_t)(n0 + row) * K + k0 + scol, &Bs[buf][cb * 512]);
    }
  };

  STAGE(0); STAGE(1); STAGE(2);
  for (int kt = 0; kt < NT; ++kt) {
    if (kt < NT - 2)       asm volatile("s_waitcnt vmcnt(8)" ::: "memory");
    else if (kt == NT - 2) asm volatile("s_waitcnt vmcnt(4)" ::: "memory");
    else                   asm volatile("s_waitcnt vmcnt(0)" ::: "memory");
    __builtin_amdgcn_s_barrier();
    if (kt + 3 < NT) STAGE(kt + 3);
    const f16* as = &As[kt & 3][0];
    const f16* bs = &Bs[kt & 3][0];
    f16x8 af[8], bf[4];
    #pragma unroll
    for (int mt = 0; mt < 8; ++mt)
      af[mt] = *(const f16x8*)&as[(wm * 128 + mt * 16 + lr) * 32 + hi * 8];
    #pragma unroll
    for (int nt = 0; nt < 4; ++nt)
      bf[nt] = *(const f16x8*)&bs[(wn * 64 + nt * 16 + lr) * 32 + hi * 8];
    __builtin_amdgcn_s_setprio(1);
    #pragma unroll
    for (int mt = 0; mt < 8; ++mt)
      #pragma unroll
      for (int nt = 0; nt < 4; ++nt)
        acc[mt][nt] = __builtin_amdgcn_mfma_f32_16x16x32_f16(af[mt], bf[nt], acc[mt][nt], 0, 0, 0);
    __builtin_amdgcn_s_setprio(0);
  }

  #pragma unroll
  for (int nt = 0; nt < 4; ++nt) {
    int col = n0 + wn * 64 + nt * 16 + lr;
    float bv = bias[col];
    #pragma unroll
    for (int mt = 0; mt < 8; ++mt) {
      int row = m0 + wm * 128 + mt * 16 + hi * 4;
      #pragma unroll
      for (int p = 0; p < 4; ++p)
        C[(size_t)(row + p) * N + col] = acc[mt][nt][p] + bv;
    }
  }
}

// ---------------- persistent LSTM recurrence (v5: fence-free, 1-wave poll) --------
// 64 blocks x 512 threads (8 waves). Block bid owns 16 hidden units (64 gate rows).
// W_hh fragments in VGPRs (wave wid owns k-range wid*128..+128).
// Cross-block data (HS, bar) moves via agent-scope atomics (bypass non-coherent
// XCD L2) -> no fences/wbl2/buffer_inv; XG2/Whh stay L2-resident across steps.
// ONLY WAVE 0 polls the flags (64 polling waves grid-wide) to cut reader
// contention at the IF coherence point during store visibility.
__global__ __launch_bounds__(512, 1) void lstm_kernel(
    const f16* __restrict__ Whh16,   // [4096][1024]
    const float* __restrict__ XG2,   // [g][b][t] : ((g*32)+b)*128+t
    const f16* __restrict__ h0f,     // [32][1024]
    f16* __restrict__ HS,            // [BT][1024] rows = b*128+t
    unsigned int* __restrict__ bar) {// bar[0..63]: per-block completed-step flags
  const int bid = blockIdx.x, tid = threadIdx.x;
  const int lane = tid & 63, wid = tid >> 6;
  const int lr = lane & 15, hi = lane >> 4;
  const int j0 = bid * 16;
  __shared__ f16 hl[32][1032];           // batch-major h tile, +8 halves pad
  __shared__ float part[8][64][33];      // per-wave K-partials

  // preload W fragments (once): wave wid covers k in [wid*128, wid*128+128)
  f16x8 wfrag[4][4];
  #pragma unroll
  for (int rt = 0; rt < 4; ++rt) {                 // rt = gate q; row u = lr
    int g = rt * HID + j0 + lr;
    #pragma unroll
    for (int kk = 0; kk < 4; ++kk)
      wfrag[rt][kk] = *(const f16x8*)(Whh16 + (size_t)g * HID + wid * 128 + kk * 32 + hi * 8);
  }

  const int ub = tid & 15, bb = tid >> 4;          // thread owns (unit ub, batch bb)
  float creg = 0.f;

  for (int t = 0; t < Tt; ++t) {
    // ---- XG prefetch (normal cached loads; line holds 32 t-values -> L2 hits) ----
    float xg[4];
    #pragma unroll
    for (int q = 0; q < 4; ++q)
      xg[q] = XG2[((size_t)(q * HID + j0 + ub) * 32 + bb) * 128 + t];

    // ---- wait for all 64 blocks' h_{t-1}: wave 0 polls, barrier releases rest ----
    if (t > 0) {
      if (wid == 0) {
        const unsigned tgt = (unsigned)t;
        for (;;) {
          unsigned f = __hip_atomic_load(&bar[lane], __ATOMIC_RELAXED, __HIP_MEMORY_SCOPE_AGENT);
          if (__all(f >= tgt)) break;
        }
      }
      __syncthreads();
    }

    // ---- stage h_{t-1}: wave wid loads batch rows 4*wid..+4 (coherent 8B loads) ----
    {
      unsigned long long tmp[4][4];
      #pragma unroll
      for (int r = 0; r < 4; ++r) {
        int row = wid * 4 + r;
        const f16* hb = (t == 0) ? (h0f + (size_t)row * HID)
                                 : (HS + ((size_t)row * Tt + (t - 1)) * HID);
        #pragma unroll
        for (int c = 0; c < 4; ++c)
          tmp[r][c] = __hip_atomic_load((const unsigned long long*)hb + c * 64 + lane,
                                        __ATOMIC_RELAXED, __HIP_MEMORY_SCOPE_AGENT);
      }
      #pragma unroll
      for (int r = 0; r < 4; ++r) {
        int row = wid * 4 + r;
        #pragma unroll
        for (int c = 0; c < 4; ++c)
          *(unsigned long long*)&hl[row][(c * 64 + lane) * 4] = tmp[r][c];
      }
    }
    __syncthreads();

    // ---- gate MFMA: C[64 gate rows][32 batches], this wave's k-eighth ----
    {
      f32x4 acc[4][2] = {};
      #pragma unroll
      for (int kk = 0; kk < 4; ++kk) {
        int ko = wid * 128 + kk * 32 + hi * 8;
        f16x8 bf0 = *(const f16x8*)&hl[lr][ko];
        f16x8 bf1 = *(const f16x8*)&hl[16 + lr][ko];
        #pragma unroll
        for (int rt = 0; rt < 4; ++rt) {
          acc[rt][0] = __builtin_amdgcn_mfma_f32_16x16x32_f16(wfrag[rt][kk], bf0, acc[rt][0], 0, 0, 0);
          acc[rt][1] = __builtin_amdgcn_mfma_f32_16x16x32_f16(wfrag[rt][kk], bf1, acc[rt][1], 0, 0, 0);
        }
      }
      #pragma unroll
      for (int rt = 0; rt < 4; ++rt)
        #pragma unroll
        for (int bt = 0; bt < 2; ++bt)
          #pragma unroll
          for (int p = 0; p < 4; ++p)
            part[wid][rt * 16 + hi * 4 + p][bt * 16 + lr] = acc[rt][bt][p];
    }
    __syncthreads();

    // ---- LSTM update: thread (ub, bb); h store is agent-coherent 2B ----
    {
      float g4[4];
      #pragma unroll
      for (int q = 0; q < 4; ++q) {
        int i = q * 16 + ub;
        float s = xg[q];
        #pragma unroll
        for (int w = 0; w < 8; ++w) s += part[w][i][bb];
        g4[q] = s;
      }
      float ig = 1.f / (1.f + __expf(-g4[0]));
      float fg = 1.f / (1.f + __expf(-g4[1]));
      float gg = tanhf(g4[2]);
      float og = 1.f / (1.f + __expf(-g4[3]));
      creg = fg * creg + ig * gg;
      float h = og * tanhf(creg);
      union { f16 h; unsigned short u; } cv;
      cv.h = (f16)h;
      __hip_atomic_store((unsigned short*)&HS[((size_t)bb * Tt + t) * HID + j0 + ub],
                         cv.u, __ATOMIC_RELAXED, __HIP_MEMORY_SCOPE_AGENT);
    }

    // ---- post completion flag (no fences: waitcnt + barrier order the stores) ----
    if (t != Tt - 1) {
      asm volatile("s_waitcnt vmcnt(0)" ::: "memory");  // my h stores are at IF
      __syncthreads();                                  // => all threads' are
      if (tid == 0)
        __hip_atomic_store(&bar[bid], (unsigned)(t + 1),
                           __ATOMIC_RELAXED, __HIP_MEMORY_SCOPE_AGENT);
    }
  }
}

extern "C" void kernel_launch(void* const* d_in, const int* in_sizes, int n_in,
                              void* d_out, int out_size, void* d_ws, size_t ws_size,
                              hipStream_t stream) {
  const float* z     = (const float*)d_in[0];
  const int*   x     = (const int*)d_in[1];
  const float* W_h   = (const float*)d_in[2];
  const float* b_h   = (const float*)d_in[3];
  const float* emb   = (const float*)d_in[4];
  const float* W_ih  = (const float*)d_in[5];
  const float* W_hh  = (const float*)d_in[6];
  const float* b_ih  = (const float*)d_in[7];
  const float* b_hh  = (const float*)d_in[8];
  const float* W_out = (const float*)d_in[9];
  const float* b_out = (const float*)d_in[10];
  float* out = (float*)d_out;

  char* ws = (char*)d_ws;
  size_t off = 0;
  auto carve = [&](size_t n) { char* p = ws + off; off += (n + 255) & ~(size_t)255; return p; };
  f16*   E16    = (f16*)carve((size_t)BT * DE * 2);     // 4 MB
  f16*   Wih16  = (f16*)carve((size_t)G4 * DE * 2);     // 4 MB
  f16*   Whh16  = (f16*)carve((size_t)G4 * HID * 2);    // 8 MB
  f16*   Wout16 = (f16*)carve((size_t)VOC * HID * 2);   // 64 MB
  float* XG2    = (float*)carve((size_t)BT * G4 * 4);   // 64 MB, [g][b][t]
  f16*   HS     = (f16*)carve((size_t)BT * HID * 2);    // 8 MB
  f16*   h0f    = (f16*)carve((size_t)Bb * HID * 2);
  float* bs     = (float*)carve((size_t)G4 * 4);
  unsigned* bar = (unsigned*)carve(256);

  (void)hipMemsetAsync(bar, 0, 256, stream);   // reset grid flags each call

  cvt_kernel<<<2048, 256, 0, stream>>>(W_ih,  Wih16,  G4 * DE / 4);
  cvt_kernel<<<2048, 256, 0, stream>>>(W_hh,  Whh16,  G4 * HID / 4);
  cvt_kernel<<<2048, 256, 0, stream>>>(W_out, Wout16, VOC * HID / 4);
  gather_kernel<<<BT * DE / 8 / 256, 256, 0, stream>>>(emb, x, E16);
  bsum_kernel<<<16, 256, 0, stream>>>(b_ih, b_hh, bs, G4);
  h0_kernel<<<128, 256, 0, stream>>>(z, W_h, b_h, h0f);

  dim3 g1(G4 / 128, BT / 128);     // 32 x 32
  gemm_kernel<true><<<g1, 256, 0, stream>>>(E16, Wih16, bs, XG2, BT, G4, DE);

  lstm_kernel<<<NB, 512, 0, stream>>>(Whh16, XG2, h0f, HS, bar);

  dim3 g2(VOC / 256, BT / 256);    // 125 x 16
  gemm256_kernel<<<g2, 512, 0, stream>>>(HS, Wout16, b_out, out, BT, VOC, HID);
}

// Round 12
// 1081.205 us; speedup vs baseline: 1.3541x; 1.0207x over previous
//
#include <hip/hip_runtime.h>

typedef _Float16 f16;
typedef _Float16 f16x8 __attribute__((ext_vector_type(8)));
typedef _Float16 f16x4 __attribute__((ext_vector_type(4)));
typedef float    f32x4 __attribute__((ext_vector_type(4)));
typedef unsigned long long ull;

static constexpr int Bb  = 32;
static constexpr int Tt  = 128;
static constexpr int HID = 1024;
static constexpr int ZD  = 256;
static constexpr int DE  = 512;
static constexpr int VOC = 32000;
static constexpr int BT  = Bb * Tt;   // 4096
static constexpr int G4  = 4 * HID;   // 4096
static constexpr int NB  = 64;        // lstm blocks (16 hidden units each)

// ---- async global->LDS, 16B per lane; LDS dest = wave-uniform base + lane*16 ----
__device__ __forceinline__ void gld_lds16(const void* g, void* l) {
  __builtin_amdgcn_global_load_lds((const __attribute__((address_space(1))) unsigned int*)g,
                                   (__attribute__((address_space(3))) unsigned int*)l,
                                   16, 0, 0);
}

// ---------------- f32 -> f16 convert (vectorized) ----------------
__global__ void cvt_kernel(const float* __restrict__ s, f16* __restrict__ d, int n4) {
  int i = blockIdx.x * blockDim.x + threadIdx.x;
  int st = gridDim.x * blockDim.x;
  for (; i < n4; i += st) {
    float4 v = ((const float4*)s)[i];
    f16x4 o = { (f16)v.x, (f16)v.y, (f16)v.z, (f16)v.w };
    ((f16x4*)d)[i] = o;
  }
}

// ---------------- embedding gather -> f16 ----------------
__global__ void gather_kernel(const float* __restrict__ emb, const int* __restrict__ x,
                              f16* __restrict__ E) {
  int g = blockIdx.x * 256 + threadIdx.x;   // BT*DE/8 threads
  int m = g >> 6, seg = (g & 63) * 8;
  int idx = x[m];
  const float* src = emb + (size_t)idx * DE + seg;
  float4 a = *(const float4*)src;
  float4 b = *(const float4*)(src + 4);
  f16x8 o = { (f16)a.x,(f16)a.y,(f16)a.z,(f16)a.w,(f16)b.x,(f16)b.y,(f16)b.z,(f16)b.w };
  *(f16x8*)(E + (size_t)m * DE + seg) = o;
}

// ---------------- bias sum ----------------
__global__ void bsum_kernel(const float* __restrict__ a, const float* __restrict__ b,
                            float* __restrict__ o, int n) {
  int i = blockIdx.x * blockDim.x + threadIdx.x;
  if (i < n) o[i] = a[i] + b[i];
}

// ---------------- h0 = tanh(z @ W_h^T + b_h), store f16 ----------------
__global__ __launch_bounds__(256) void h0_kernel(const float* __restrict__ z,
                                                 const float* __restrict__ W_h,
                                                 const float* __restrict__ b_h,
                                                 f16* __restrict__ h0f) {
  __shared__ float zs[32][260];
  __shared__ float wsl[8][260];
  const int jc = blockIdx.x, tid = threadIdx.x;
  #pragma unroll
  for (int it = 0; it < 8; ++it) {
    int idx = it * 256 + tid;
    float4 v = ((const float4*)z)[idx];
    int b = idx >> 6, k = (idx & 63) * 4;
    zs[b][k] = v.x; zs[b][k+1] = v.y; zs[b][k+2] = v.z; zs[b][k+3] = v.w;
  }
  #pragma unroll
  for (int it = 0; it < 2; ++it) {
    int idx = it * 256 + tid;
    float4 v = ((const float4*)(W_h + (size_t)jc * 8 * ZD))[idx];
    int r = idx >> 6, k = (idx & 63) * 4;
    wsl[r][k] = v.x; wsl[r][k+1] = v.y; wsl[r][k+2] = v.z; wsl[r][k+3] = v.w;
  }
  __syncthreads();
  const int b = tid >> 3, jj = tid & 7;
  const int j = jc * 8 + jj;
  float acc = b_h[j];
  for (int k = 0; k < ZD; ++k) acc += zs[b][k] * wsl[jj][k];
  h0f[(size_t)b * HID + j] = (f16)tanhf(acc);
}

// ---------------- GEMM 128x128 (proven): C = A @ B^T + bias, XGOUT variant ------
template <bool XGOUT>
__global__ __launch_bounds__(256, 2) void gemm_kernel(
    const f16* __restrict__ A, const f16* __restrict__ B,
    const float* __restrict__ bias, float* __restrict__ C,
    int M, int N, int K) {
  __shared__ f16 As[128 * 64];
  __shared__ f16 Bs[128 * 64];
  const int n0 = blockIdx.x * 128, m0 = blockIdx.y * 128;
  const int tid = threadIdx.x, wid = tid >> 6, lane = tid & 63;
  const int wm = wid >> 1, wn = wid & 1;
  const int sr = lane >> 3, sk = (lane & 7) * 8;
  f32x4 acc[4][4] = {};
  for (int k0 = 0; k0 < K; k0 += 64) {
    __syncthreads();
    #pragma unroll
    for (int i = 0; i < 4; ++i) {
      int rr = (wid * 4 + i) * 8;
      gld_lds16(A + (size_t)(m0 + rr + sr) * K + k0 + sk, &As[rr * 64]);
      gld_lds16(B + (size_t)(n0 + rr + sr) * K + k0 + sk, &Bs[rr * 64]);
    }
    __syncthreads();
    #pragma unroll
    for (int ks = 0; ks < 2; ++ks) {
      f16x8 af[4], bf[4];
      #pragma unroll
      for (int mt = 0; mt < 4; ++mt)
        af[mt] = *(const f16x8*)&As[(wm * 64 + mt * 16 + (lane & 15)) * 64 + ks * 32 + (lane >> 4) * 8];
      #pragma unroll
      for (int nt = 0; nt < 4; ++nt)
        bf[nt] = *(const f16x8*)&Bs[(wn * 64 + nt * 16 + (lane & 15)) * 64 + ks * 32 + (lane >> 4) * 8];
      #pragma unroll
      for (int mt = 0; mt < 4; ++mt)
        #pragma unroll
        for (int nt = 0; nt < 4; ++nt)
          acc[mt][nt] = __builtin_amdgcn_mfma_f32_16x16x32_f16(af[mt], bf[nt], acc[mt][nt], 0, 0, 0);
    }
  }
  #pragma unroll
  for (int nt = 0; nt < 4; ++nt) {
    int col = n0 + wn * 64 + nt * 16 + (lane & 15);
    float bv = bias[col];
    #pragma unroll
    for (int mt = 0; mt < 4; ++mt) {
      int row = m0 + wm * 64 + mt * 16 + (lane >> 4) * 4;
      if (XGOUT) {
        int b = row >> 7, t0 = row & 127;
        float4 v = { acc[mt][nt][0] + bv, acc[mt][nt][1] + bv,
                     acc[mt][nt][2] + bv, acc[mt][nt][3] + bv };
        *(float4*)&C[((size_t)col * 32 + b) * 128 + t0] = v;
      } else {
        #pragma unroll
        for (int p = 0; p < 4; ++p)
          C[(size_t)(row + p) * N + col] = acc[mt][nt][p] + bv;
      }
    }
  }
}

// ---------------- GEMM 256x256, BK=32, 4-buf ring, counted vmcnt + T2 swizzle ----
// 512 threads = 8 waves (2M x 4N); per-wave output 128x64 (8x4 16x16 frags).
// Ring of 4 LDS buffers, prefetch depth 3, vmcnt(8) counted (never 0 mid-loop),
// raw s_barrier, setprio around MFMA.
// T2 swizzle (rule #21, both-sides): LDS dest stays LINEAR (global_load_lds);
// the per-lane GLOBAL source column is pre-swizzled (scol = ((lane&3)^((lane>>3)&3))*8,
// i.e. XOR byte-bits 4-5 with row-bits 1-2), and ds_read applies the same XOR
// (slot = hi ^ ((lr>>1)&3)). Bank-quad = 16*(lr&1) + 4*(hi^((lr>>1)&3)): 8 slots
// x 2 lanes = 2-way (free) instead of 8-way.
__global__ __launch_bounds__(512, 2) void gemm256_kernel(
    const f16* __restrict__ A,   // [M][K]
    const f16* __restrict__ B,   // [N][K]
    const float* __restrict__ bias, float* __restrict__ C,
    int M, int N, int K) {
  __shared__ __align__(16) f16 As[4][256 * 32];
  __shared__ __align__(16) f16 Bs[4][256 * 32];
  const int n0 = blockIdx.x * 256, m0 = blockIdx.y * 256;
  const int tid = threadIdx.x, wid = tid >> 6, lane = tid & 63;
  const int wm = wid >> 2, wn = wid & 3;
  const int lr = lane & 15, hi = lane >> 4;
  const int srow = lane >> 2;                           // staging: 16 rows x 64B
  const int scol = ((lane & 3) ^ ((lane >> 3) & 3)) * 8;// pre-swizzled source col
  const int sx   = (hi ^ ((lr >> 1) & 3)) * 8;          // swizzled read slot
  const int NT = K >> 5;                                // BK=32

  f32x4 acc[8][4] = {};

  auto STAGE = [&](int kt) {
    const int k0 = kt << 5, buf = kt & 3;
    #pragma unroll
    for (int i = 0; i < 2; ++i) {
      int cb = wid * 2 + i;                             // 0..15, 16-row group
      int row = cb * 16 + srow;
      gld_lds16(A + (size_t)(m0 + row) * K + k0 + scol, &As[buf][cb * 512]);
      gld_lds16(B + (size_t)(n0 + row) * K + k0 + scol, &Bs[buf][cb * 512]);
    }
  };

  STAGE(0); STAGE(1); STAGE(2);
  for (int kt = 0; kt < NT; ++kt) {
    if (kt < NT - 2)       asm volatile("s_waitcnt vmcnt(8)" ::: "memory");
    else if (kt == NT - 2) asm volatile("s_waitcnt vmcnt(4)" ::: "memory");
    else                   asm volatile("s_waitcnt vmcnt(0)" ::: "memory");
    __builtin_amdgcn_s_barrier();
    if (kt + 3 < NT) STAGE(kt + 3);
    const f16* as = &As[kt & 3][0];
    const f16* bs = &Bs[kt & 3][0];
    f16x8 af[8], bf[4];
    #pragma unroll
    for (int mt = 0; mt < 8; ++mt)
      af[mt] = *(const f16x8*)&as[(wm * 128 + mt * 16 + lr) * 32 + sx];
    #pragma unroll
    for (int nt = 0; nt < 4; ++nt)
      bf[nt] = *(const f16x8*)&bs[(wn * 64 + nt * 16 + lr) * 32 + sx];
    __builtin_amdgcn_s_setprio(1);
    #pragma unroll
    for (int mt = 0; mt < 8; ++mt)
      #pragma unroll
      for (int nt = 0; nt < 4; ++nt)
        acc[mt][nt] = __builtin_amdgcn_mfma_f32_16x16x32_f16(af[mt], bf[nt], acc[mt][nt], 0, 0, 0);
    __builtin_amdgcn_s_setprio(0);
  }

  #pragma unroll
  for (int nt = 0; nt < 4; ++nt) {
    int col = n0 + wn * 64 + nt * 16 + lr;
    float bv = bias[col];
    #pragma unroll
    for (int mt = 0; mt < 8; ++mt) {
      int row = m0 + wm * 128 + mt * 16 + hi * 4;
      #pragma unroll
      for (int p = 0; p < 4; ++p)
        C[(size_t)(row + p) * N + col] = acc[mt][nt][p] + bv;
    }
  }
}

// ---------------- persistent LSTM recurrence (v5: fence-free, 1-wave poll) --------
// 64 blocks x 512 threads (8 waves). Block bid owns 16 hidden units (64 gate rows).
// W_hh fragments in VGPRs (wave wid owns k-range wid*128..+128).
// Cross-block data (HS, bar) moves via agent-scope atomics (bypass non-coherent
// XCD L2) -> no fences/wbl2/buffer_inv; XG2/Whh stay L2-resident across steps.
// ONLY WAVE 0 polls the flags (64 polling waves grid-wide) to cut reader
// contention at the IF coherence point during store visibility.
__global__ __launch_bounds__(512, 1) void lstm_kernel(
    const f16* __restrict__ Whh16,   // [4096][1024]
    const float* __restrict__ XG2,   // [g][b][t] : ((g*32)+b)*128+t
    const f16* __restrict__ h0f,     // [32][1024]
    f16* __restrict__ HS,            // [BT][1024] rows = b*128+t
    unsigned int* __restrict__ bar) {// bar[0..63]: per-block completed-step flags
  const int bid = blockIdx.x, tid = threadIdx.x;
  const int lane = tid & 63, wid = tid >> 6;
  const int lr = lane & 15, hi = lane >> 4;
  const int j0 = bid * 16;
  __shared__ f16 hl[32][1032];           // batch-major h tile, +8 halves pad
  __shared__ float part[8][64][33];      // per-wave K-partials

  // preload W fragments (once): wave wid covers k in [wid*128, wid*128+128)
  f16x8 wfrag[4][4];
  #pragma unroll
  for (int rt = 0; rt < 4; ++rt) {                 // rt = gate q; row u = lr
    int g = rt * HID + j0 + lr;
    #pragma unroll
    for (int kk = 0; kk < 4; ++kk)
      wfrag[rt][kk] = *(const f16x8*)(Whh16 + (size_t)g * HID + wid * 128 + kk * 32 + hi * 8);
  }

  const int ub = tid & 15, bb = tid >> 4;          // thread owns (unit ub, batch bb)
  float creg = 0.f;

  for (int t = 0; t < Tt; ++t) {
    // ---- XG prefetch (normal cached loads; line holds 32 t-values -> L2 hits) ----
    float xg[4];
    #pragma unroll
    for (int q = 0; q < 4; ++q)
      xg[q] = XG2[((size_t)(q * HID + j0 + ub) * 32 + bb) * 128 + t];

    // ---- wait for all 64 blocks' h_{t-1}: wave 0 polls, barrier releases rest ----
    if (t > 0) {
      if (wid == 0) {
        const unsigned tgt = (unsigned)t;
        for (;;) {
          unsigned f = __hip_atomic_load(&bar[lane], __ATOMIC_RELAXED, __HIP_MEMORY_SCOPE_AGENT);
          if (__all(f >= tgt)) break;
        }
      }
      __syncthreads();
    }

    // ---- stage h_{t-1}: wave wid loads batch rows 4*wid..+4 (coherent 8B loads) ----
    {
      unsigned long long tmp[4][4];
      #pragma unroll
      for (int r = 0; r < 4; ++r) {
        int row = wid * 4 + r;
        const f16* hb = (t == 0) ? (h0f + (size_t)row * HID)
                                 : (HS + ((size_t)row * Tt + (t - 1)) * HID);
        #pragma unroll
        for (int c = 0; c < 4; ++c)
          tmp[r][c] = __hip_atomic_load((const unsigned long long*)hb + c * 64 + lane,
                                        __ATOMIC_RELAXED, __HIP_MEMORY_SCOPE_AGENT);
      }
      #pragma unroll
      for (int r = 0; r < 4; ++r) {
        int row = wid * 4 + r;
        #pragma unroll
        for (int c = 0; c < 4; ++c)
          *(unsigned long long*)&hl[row][(c * 64 + lane) * 4] = tmp[r][c];
      }
    }
    __syncthreads();

    // ---- gate MFMA: C[64 gate rows][32 batches], this wave's k-eighth ----
    {
      f32x4 acc[4][2] = {};
      #pragma unroll
      for (int kk = 0; kk < 4; ++kk) {
        int ko = wid * 128 + kk * 32 + hi * 8;
        f16x8 bf0 = *(const f16x8*)&hl[lr][ko];
        f16x8 bf1 = *(const f16x8*)&hl[16 + lr][ko];
        #pragma unroll
        for (int rt = 0; rt < 4; ++rt) {
          acc[rt][0] = __builtin_amdgcn_mfma_f32_16x16x32_f16(wfrag[rt][kk], bf0, acc[rt][0], 0, 0, 0);
          acc[rt][1] = __builtin_amdgcn_mfma_f32_16x16x32_f16(wfrag[rt][kk], bf1, acc[rt][1], 0, 0, 0);
        }
      }
      #pragma unroll
      for (int rt = 0; rt < 4; ++rt)
        #pragma unroll
        for (int bt = 0; bt < 2; ++bt)
          #pragma unroll
          for (int p = 0; p < 4; ++p)
            part[wid][rt * 16 + hi * 4 + p][bt * 16 + lr] = acc[rt][bt][p];
    }
    __syncthreads();

    // ---- LSTM update: thread (ub, bb); h store is agent-coherent 2B ----
    {
      float g4[4];
      #pragma unroll
      for (int q = 0; q < 4; ++q) {
        int i = q * 16 + ub;
        float s = xg[q];
        #pragma unroll
        for (int w = 0; w < 8; ++w) s += part[w][i][bb];
        g4[q] = s;
      }
      float ig = 1.f / (1.f + __expf(-g4[0]));
      float fg = 1.f / (1.f + __expf(-g4[1]));
      float gg = tanhf(g4[2]);
      float og = 1.f / (1.f + __expf(-g4[3]));
      creg = fg * creg + ig * gg;
      float h = og * tanhf(creg);
      union { f16 h; unsigned short u; } cv;
      cv.h = (f16)h;
      __hip_atomic_store((unsigned short*)&HS[((size_t)bb * Tt + t) * HID + j0 + ub],
                         cv.u, __ATOMIC_RELAXED, __HIP_MEMORY_SCOPE_AGENT);
    }

    // ---- post completion flag (no fences: waitcnt + barrier order the stores) ----
    if (t != Tt - 1) {
      asm volatile("s_waitcnt vmcnt(0)" ::: "memory");  // my h stores are at IF
      __syncthreads();                                  // => all threads' are
      if (tid == 0)
        __hip_atomic_store(&bar[bid], (unsigned)(t + 1),
                           __ATOMIC_RELAXED, __HIP_MEMORY_SCOPE_AGENT);
    }
  }
}

extern "C" void kernel_launch(void* const* d_in, const int* in_sizes, int n_in,
                              void* d_out, int out_size, void* d_ws, size_t ws_size,
                              hipStream_t stream) {
  const float* z     = (const float*)d_in[0];
  const int*   x     = (const int*)d_in[1];
  const float* W_h   = (const float*)d_in[2];
  const float* b_h   = (const float*)d_in[3];
  const float* emb   = (const float*)d_in[4];
  const float* W_ih  = (const float*)d_in[5];
  const float* W_hh  = (const float*)d_in[6];
  const float* b_ih  = (const float*)d_in[7];
  const float* b_hh  = (const float*)d_in[8];
  const float* W_out = (const float*)d_in[9];
  const float* b_out = (const float*)d_in[10];
  float* out = (float*)d_out;

  char* ws = (char*)d_ws;
  size_t off = 0;
  auto carve = [&](size_t n) { char* p = ws + off; off += (n + 255) & ~(size_t)255; return p; };
  f16*   E16    = (f16*)carve((size_t)BT * DE * 2);     // 4 MB
  f16*   Wih16  = (f16*)carve((size_t)G4 * DE * 2);     // 4 MB
  f16*   Whh16  = (f16*)carve((size_t)G4 * HID * 2);    // 8 MB
  f16*   Wout16 = (f16*)carve((size_t)VOC * HID * 2);   // 64 MB
  float* XG2    = (float*)carve((size_t)BT * G4 * 4);   // 64 MB, [g][b][t]
  f16*   HS     = (f16*)carve((size_t)BT * HID * 2);    // 8 MB
  f16*   h0f    = (f16*)carve((size_t)Bb * HID * 2);
  float* bs     = (float*)carve((size_t)G4 * 4);
  unsigned* bar = (unsigned*)carve(256);

  (void)hipMemsetAsync(bar, 0, 256, stream);   // reset grid flags each call

  cvt_kernel<<<2048, 256, 0, stream>>>(W_ih,  Wih16,  G4 * DE / 4);
  cvt_kernel<<<2048, 256, 0, stream>>>(W_hh,  Whh16,  G4 * HID / 4);
  cvt_kernel<<<2048, 256, 0, stream>>>(W_out, Wout16, VOC * HID / 4);
  gather_kernel<<<BT * DE / 8 / 256, 256, 0, stream>>>(emb, x, E16);
  bsum_kernel<<<16, 256, 0, stream>>>(b_ih, b_hh, bs, G4);
  h0_kernel<<<128, 256, 0, stream>>>(z, W_h, b_h, h0f);

  dim3 g1(G4 / 128, BT / 128);     // 32 x 32
  gemm_kernel<true><<<g1, 256, 0, stream>>>(E16, Wih16, bs, XG2, BT, G4, DE);

  lstm_kernel<<<NB, 512, 0, stream>>>(Whh16, XG2, h0f, HS, bar);

  dim3 g2(VOC / 256, BT / 256);    // 125 x 16
  gemm256_kernel<<<g2, 512, 0, stream>>>(HS, Wout16, b_out, out, BT, VOC, HID);
}

// Round 13
// 1038.307 us; speedup vs baseline: 1.4100x; 1.0413x over previous
//
#include <hip/hip_runtime.h>

typedef _Float16 f16;
typedef _Float16 f16x8 __attribute__((ext_vector_type(8)));
typedef _Float16 f16x4 __attribute__((ext_vector_type(4)));
typedef float    f32x4 __attribute__((ext_vector_type(4)));
typedef unsigned long long ull;

static constexpr int Bb  = 32;
static constexpr int Tt  = 128;
static constexpr int HID = 1024;
static constexpr int ZD  = 256;
static constexpr int DE  = 512;
static constexpr int VOC = 32000;
static constexpr int BT  = Bb * Tt;   // 4096
static constexpr int G4  = 4 * HID;   // 4096
static constexpr int NLSTM = 64;      // lstm-role blocks (16 hidden units each)
static constexpr int NTILES = (BT / 256) * (VOC / 256);  // 16 * 125 = 2000
// HS layout is T-MAJOR: row m' = t*32 + b, so a 256-row GEMM M-tile = 8 steps.

// ---- async global->LDS, 16B per lane; LDS dest = wave-uniform base + lane*16 ----
__device__ __forceinline__ void gld_lds16(const void* g, void* l) {
  __builtin_amdgcn_global_load_lds((const __attribute__((address_space(1))) unsigned int*)g,
                                   (__attribute__((address_space(3))) unsigned int*)l,
                                   16, 0, 0);
}

// ---------------- f32 -> f16 convert (vectorized) ----------------
__global__ void cvt_kernel(const float* __restrict__ s, f16* __restrict__ d, int n4) {
  int i = blockIdx.x * blockDim.x + threadIdx.x;
  int st = gridDim.x * blockDim.x;
  for (; i < n4; i += st) {
    float4 v = ((const float4*)s)[i];
    f16x4 o = { (f16)v.x, (f16)v.y, (f16)v.z, (f16)v.w };
    ((f16x4*)d)[i] = o;
  }
}

// ---------------- embedding gather -> f16 ----------------
__global__ void gather_kernel(const float* __restrict__ emb, const int* __restrict__ x,
                              f16* __restrict__ E) {
  int g = blockIdx.x * 256 + threadIdx.x;   // BT*DE/8 threads
  int m = g >> 6, seg = (g & 63) * 8;
  int idx = x[m];
  const float* src = emb + (size_t)idx * DE + seg;
  float4 a = *(const float4*)src;
  float4 b = *(const float4*)(src + 4);
  f16x8 o = { (f16)a.x,(f16)a.y,(f16)a.z,(f16)a.w,(f16)b.x,(f16)b.y,(f16)b.z,(f16)b.w };
  *(f16x8*)(E + (size_t)m * DE + seg) = o;
}

// ---------------- bias sum ----------------
__global__ void bsum_kernel(const float* __restrict__ a, const float* __restrict__ b,
                            float* __restrict__ o, int n) {
  int i = blockIdx.x * blockDim.x + threadIdx.x;
  if (i < n) o[i] = a[i] + b[i];
}

// ---------------- h0 = tanh(z @ W_h^T + b_h), store f16 ----------------
__global__ __launch_bounds__(256) void h0_kernel(const float* __restrict__ z,
                                                 const float* __restrict__ W_h,
                                                 const float* __restrict__ b_h,
                                                 f16* __restrict__ h0f) {
  __shared__ float zs[32][260];
  __shared__ float wsl[8][260];
  const int jc = blockIdx.x, tid = threadIdx.x;
  #pragma unroll
  for (int it = 0; it < 8; ++it) {
    int idx = it * 256 + tid;
    float4 v = ((const float4*)z)[idx];
    int b = idx >> 6, k = (idx & 63) * 4;
    zs[b][k] = v.x; zs[b][k+1] = v.y; zs[b][k+2] = v.z; zs[b][k+3] = v.w;
  }
  #pragma unroll
  for (int it = 0; it < 2; ++it) {
    int idx = it * 256 + tid;
    float4 v = ((const float4*)(W_h + (size_t)jc * 8 * ZD))[idx];
    int r = idx >> 6, k = (idx & 63) * 4;
    wsl[r][k] = v.x; wsl[r][k+1] = v.y; wsl[r][k+2] = v.z; wsl[r][k+3] = v.w;
  }
  __syncthreads();
  const int b = tid >> 3, jj = tid & 7;
  const int j = jc * 8 + jj;
  float acc = b_h[j];
  for (int k = 0; k < ZD; ++k) acc += zs[b][k] * wsl[jj][k];
  h0f[(size_t)b * HID + j] = (f16)tanhf(acc);
}

// ---------------- GEMM 128x128 (proven): C = A @ B^T + bias, XG output layout ---
__global__ __launch_bounds__(256, 2) void gemmxg_kernel(
    const f16* __restrict__ A, const f16* __restrict__ B,
    const float* __restrict__ bias, float* __restrict__ C,
    int M, int N, int K) {
  __shared__ f16 As[128 * 64];
  __shared__ f16 Bs[128 * 64];
  const int n0 = blockIdx.x * 128, m0 = blockIdx.y * 128;
  const int tid = threadIdx.x, wid = tid >> 6, lane = tid & 63;
  const int wm = wid >> 1, wn = wid & 1;
  const int sr = lane >> 3, sk = (lane & 7) * 8;
  f32x4 acc[4][4] = {};
  for (int k0 = 0; k0 < K; k0 += 64) {
    __syncthreads();
    #pragma unroll
    for (int i = 0; i < 4; ++i) {
      int rr = (wid * 4 + i) * 8;
      gld_lds16(A + (size_t)(m0 + rr + sr) * K + k0 + sk, &As[rr * 64]);
      gld_lds16(B + (size_t)(n0 + rr + sr) * K + k0 + sk, &Bs[rr * 64]);
    }
    __syncthreads();
    #pragma unroll
    for (int ks = 0; ks < 2; ++ks) {
      f16x8 af[4], bf[4];
      #pragma unroll
      for (int mt = 0; mt < 4; ++mt)
        af[mt] = *(const f16x8*)&As[(wm * 64 + mt * 16 + (lane & 15)) * 64 + ks * 32 + (lane >> 4) * 8];
      #pragma unroll
      for (int nt = 0; nt < 4; ++nt)
        bf[nt] = *(const f16x8*)&Bs[(wn * 64 + nt * 16 + (lane & 15)) * 64 + ks * 32 + (lane >> 4) * 8];
      #pragma unroll
      for (int mt = 0; mt < 4; ++mt)
        #pragma unroll
        for (int nt = 0; nt < 4; ++nt)
          acc[mt][nt] = __builtin_amdgcn_mfma_f32_16x16x32_f16(af[mt], bf[nt], acc[mt][nt], 0, 0, 0);
    }
  }
  #pragma unroll
  for (int nt = 0; nt < 4; ++nt) {
    int col = n0 + wn * 64 + nt * 16 + (lane & 15);
    float bv = bias[col];
    #pragma unroll
    for (int mt = 0; mt < 4; ++mt) {
      int row = m0 + wm * 64 + mt * 16 + (lane >> 4) * 4;
      int b = row >> 7, t0 = row & 127;
      float4 v = { acc[mt][nt][0] + bv, acc[mt][nt][1] + bv,
                   acc[mt][nt][2] + bv, acc[mt][nt][3] + bv };
      *(float4*)&C[((size_t)col * 32 + b) * 128 + t0] = v;
    }
  }
}

// =================================================================================
// FUSED persistent kernel: 256 blocks x 512 threads, 1 block/CU (capacity-resident).
//   blocks 0..63 : LSTM recurrence role (v5 structure, t-major HS), then join pool.
//   blocks 64..255: GEMM workers from the start.
// Workers pull 256x256 output-GEMM tiles (mg-major => ascending t) from an atomic
// queue and wait for readiness flags (all 64 lstm flags >= 8(mg+1)) with backoff.
// A (HS) is agent-loaded (stale-L2-safe across replays) and reg-staged into LDS;
// B (Wout16) uses global_load_lds. T2 swizzle on both.
// =================================================================================
static constexpr int SM_HL   = 0;                       // f16 hl[32][1032] = 66048 B
static constexpr int SM_PART = 66048;                   // float part[8][64][33] = 67584 B
static constexpr int SM_IDX  = 133632;                  // unsigned sIdx
static constexpr int SM_SIZE = 133648;

__device__ void lstm_role(const f16* __restrict__ Whh16, const float* __restrict__ XG2,
                          const f16* __restrict__ h0f, f16* __restrict__ HS,
                          unsigned* __restrict__ bar, char* smem) {
  const int bid = blockIdx.x, tid = threadIdx.x;
  const int lane = tid & 63, wid = tid >> 6;
  const int lr = lane & 15, hi = lane >> 4;
  const int j0 = bid * 16;
  f16 (*hl)[1032] = (f16 (*)[1032])(smem + SM_HL);
  float (*part)[64][33] = (float (*)[64][33])(smem + SM_PART);

  f16x8 wfrag[4][4];
  #pragma unroll
  for (int rt = 0; rt < 4; ++rt) {
    int g = rt * HID + j0 + lr;
    #pragma unroll
    for (int kk = 0; kk < 4; ++kk)
      wfrag[rt][kk] = *(const f16x8*)(Whh16 + (size_t)g * HID + wid * 128 + kk * 32 + hi * 8);
  }

  const int ub = tid & 15, bb = tid >> 4;
  float creg = 0.f;

  for (int t = 0; t < Tt; ++t) {
    float xg[4];
    #pragma unroll
    for (int q = 0; q < 4; ++q)
      xg[q] = XG2[((size_t)(q * HID + j0 + ub) * 32 + bb) * 128 + t];

    if (t > 0) {
      if (wid == 0) {
        const unsigned tgt = (unsigned)t;
        for (;;) {
          unsigned f = __hip_atomic_load(&bar[lane], __ATOMIC_RELAXED, __HIP_MEMORY_SCOPE_AGENT);
          if (__all(f >= tgt)) break;
        }
      }
      __syncthreads();
    }

    // stage h_{t-1}: wave wid loads batch rows 4*wid..+4 (agent 8B loads); t-major HS
    {
      ull tmp[4][4];
      #pragma unroll
      for (int r = 0; r < 4; ++r) {
        int row = wid * 4 + r;
        const f16* hb = (t == 0) ? (h0f + (size_t)row * HID)
                                 : (HS + (size_t)((t - 1) * 32 + row) * HID);
        #pragma unroll
        for (int c = 0; c < 4; ++c)
          tmp[r][c] = __hip_atomic_load((const ull*)hb + c * 64 + lane,
                                        __ATOMIC_RELAXED, __HIP_MEMORY_SCOPE_AGENT);
      }
      #pragma unroll
      for (int r = 0; r < 4; ++r) {
        int row = wid * 4 + r;
        #pragma unroll
        for (int c = 0; c < 4; ++c)
          *(ull*)&hl[row][(c * 64 + lane) * 4] = tmp[r][c];
      }
    }
    __syncthreads();

    // gate MFMA: C[64 gate rows][32 batches], this wave's k-eighth
    {
      f32x4 acc[4][2] = {};
      #pragma unroll
      for (int kk = 0; kk < 4; ++kk) {
        int ko = wid * 128 + kk * 32 + hi * 8;
        f16x8 bf0 = *(const f16x8*)&hl[lr][ko];
        f16x8 bf1 = *(const f16x8*)&hl[16 + lr][ko];
        #pragma unroll
        for (int rt = 0; rt < 4; ++rt) {
          acc[rt][0] = __builtin_amdgcn_mfma_f32_16x16x32_f16(wfrag[rt][kk], bf0, acc[rt][0], 0, 0, 0);
          acc[rt][1] = __builtin_amdgcn_mfma_f32_16x16x32_f16(wfrag[rt][kk], bf1, acc[rt][1], 0, 0, 0);
        }
      }
      #pragma unroll
      for (int rt = 0; rt < 4; ++rt)
        #pragma unroll
        for (int bt = 0; bt < 2; ++bt)
          #pragma unroll
          for (int p = 0; p < 4; ++p)
            part[wid][rt * 16 + hi * 4 + p][bt * 16 + lr] = acc[rt][bt][p];
    }
    __syncthreads();

    // LSTM update: thread (ub, bb); h store agent-coherent 2B, t-major row
    {
      float g4[4];
      #pragma unroll
      for (int q = 0; q < 4; ++q) {
        int i = q * 16 + ub;
        float s = xg[q];
        #pragma unroll
        for (int w = 0; w < 8; ++w) s += part[w][i][bb];
        g4[q] = s;
      }
      float ig = 1.f / (1.f + __expf(-g4[0]));
      float fg = 1.f / (1.f + __expf(-g4[1]));
      float gg = tanhf(g4[2]);
      float og = 1.f / (1.f + __expf(-g4[3]));
      creg = fg * creg + ig * gg;
      float h = og * tanhf(creg);
      union { f16 h; unsigned short u; } cv;
      cv.h = (f16)h;
      __hip_atomic_store((unsigned short*)&HS[(size_t)(t * 32 + bb) * HID + j0 + ub],
                         cv.u, __ATOMIC_RELAXED, __HIP_MEMORY_SCOPE_AGENT);
    }

    // post completion flag for EVERY t (workers need t=127 too)
    asm volatile("s_waitcnt vmcnt(0)" ::: "memory");
    __syncthreads();
    if (tid == 0)
      __hip_atomic_store(&bar[bid], (unsigned)(t + 1),
                         __ATOMIC_RELAXED, __HIP_MEMORY_SCOPE_AGENT);
  }
}

__device__ void worker_role(const f16* __restrict__ HS, const f16* __restrict__ Wout16,
                            const float* __restrict__ b_out, float* __restrict__ out,
                            unsigned* __restrict__ bar, unsigned* __restrict__ cnt,
                            char* smem) {
  const int tid = threadIdx.x, wid = tid >> 6, lane = tid & 63;
  const int wm = wid >> 2, wn = wid & 3;
  const int lr = lane & 15, hi = lane >> 4;
  const int srow = lane >> 2;
  const int scol = ((lane & 3) ^ ((lane >> 3) & 3)) * 8;   // pre-swizzled source col
  const int sx   = (hi ^ ((lr >> 1) & 3)) * 8;             // swizzled read slot
  f16* Ab = (f16*)(smem);            // [2][256*32] halves = 32768 B
  f16* Bb = (f16*)(smem + 65536);    // [2][256*32]
  unsigned* sIdx = (unsigned*)(smem + SM_IDX);
  const int cb0 = wid * 2, cb1 = wid * 2 + 1;

  for (;;) {
    if (tid == 0) *sIdx = atomicAdd(cnt, 1u);
    __syncthreads();
    unsigned idx = *sIdx;
    if (idx >= (unsigned)NTILES) break;
    int mg = idx / 125, ng = idx - mg * 125;
    // readiness: all 64 lstm blocks completed step 8*mg+7 (flag >= 8mg+8)
    if (wid == 0) {
      const unsigned tgt = (unsigned)(8 * mg + 8);
      for (;;) {
        unsigned f = __hip_atomic_load(&bar[lane], __ATOMIC_RELAXED, __HIP_MEMORY_SCOPE_AGENT);
        if (__all(f >= tgt)) break;
        __builtin_amdgcn_s_sleep(32);
      }
    }
    __syncthreads();

    const int m0 = mg * 256, n0 = ng * 256;
    f32x4 acc[8][4] = {};
    ull ar0, ar1, ar2, ar3;

    auto LOADA = [&](int kt) {
      int k0 = kt * 32;
      const ull* s0 = (const ull*)(HS + (size_t)(m0 + cb0 * 16 + srow) * HID + k0 + scol);
      const ull* s1 = (const ull*)(HS + (size_t)(m0 + cb1 * 16 + srow) * HID + k0 + scol);
      ar0 = __hip_atomic_load(s0,     __ATOMIC_RELAXED, __HIP_MEMORY_SCOPE_AGENT);
      ar1 = __hip_atomic_load(s0 + 1, __ATOMIC_RELAXED, __HIP_MEMORY_SCOPE_AGENT);
      ar2 = __hip_atomic_load(s1,     __ATOMIC_RELAXED, __HIP_MEMORY_SCOPE_AGENT);
      ar3 = __hip_atomic_load(s1 + 1, __ATOMIC_RELAXED, __HIP_MEMORY_SCOPE_AGENT);
    };
    auto LOADB = [&](int kt) {
      int k0 = kt * 32, buf = kt & 1;
      gld_lds16(Wout16 + (size_t)(n0 + cb0 * 16 + srow) * HID + k0 + scol, Bb + buf * 8192 + cb0 * 512);
      gld_lds16(Wout16 + (size_t)(n0 + cb1 * 16 + srow) * HID + k0 + scol, Bb + buf * 8192 + cb1 * 512);
    };
    auto WRITEA = [&](int kt) {
      int buf = kt & 1;
      *(ull*)(Ab + buf * 8192 + cb0 * 512 + lane * 8)     = ar0;
      *(ull*)(Ab + buf * 8192 + cb0 * 512 + lane * 8 + 4) = ar1;
      *(ull*)(Ab + buf * 8192 + cb1 * 512 + lane * 8)     = ar2;
      *(ull*)(Ab + buf * 8192 + cb1 * 512 + lane * 8 + 4) = ar3;
    };

    // prologue
    LOADA(0); LOADB(0);
    asm volatile("s_waitcnt vmcnt(0)" ::: "memory");
    WRITEA(0);
    __syncthreads();

    for (int kt = 0; kt < 32; ++kt) {
      if (kt < 31) { LOADA(kt + 1); LOADB(kt + 1); }
      int buf = kt & 1;
      f16x8 af[8], bf[4];
      #pragma unroll
      for (int mt = 0; mt < 8; ++mt)
        af[mt] = *(const f16x8*)(Ab + buf * 8192 + (wm * 128 + mt * 16 + lr) * 32 + sx);
      #pragma unroll
      for (int nt = 0; nt < 4; ++nt)
        bf[nt] = *(const f16x8*)(Bb + buf * 8192 + (wn * 64 + nt * 16 + lr) * 32 + sx);
      __builtin_amdgcn_s_setprio(1);
      #pragma unroll
      for (int mt = 0; mt < 8; ++mt)
        #pragma unroll
        for (int nt = 0; nt < 4; ++nt)
          acc[mt][nt] = __builtin_amdgcn_mfma_f32_16x16x32_f16(af[mt], bf[nt], acc[mt][nt], 0, 0, 0);
      __builtin_amdgcn_s_setprio(0);
      if (kt < 31) {
        asm volatile("s_waitcnt vmcnt(0)" ::: "memory");
        WRITEA(kt + 1);
      }
      __syncthreads();
    }

    // epilogue: un-permute rows (m' = t*32+b -> out row b*128+t), add bias
    #pragma unroll
    for (int nt = 0; nt < 4; ++nt) {
      int col = n0 + wn * 64 + nt * 16 + lr;
      float bv = b_out[col];
      #pragma unroll
      for (int mt = 0; mt < 8; ++mt) {
        int mbase = m0 + wm * 128 + mt * 16 + hi * 4;
        #pragma unroll
        for (int p = 0; p < 4; ++p) {
          int mp = mbase + p;
          int orow = (mp & 31) * 128 + (mp >> 5);
          out[(size_t)orow * VOC + col] = acc[mt][nt][p] + bv;
        }
      }
    }
  }
}

__global__ __launch_bounds__(512, 1) void fused_kernel(
    const f16* __restrict__ Whh16, const float* __restrict__ XG2,
    const f16* __restrict__ h0f, f16* __restrict__ HS,
    const f16* __restrict__ Wout16, const float* __restrict__ b_out,
    float* __restrict__ out, unsigned* __restrict__ bar, unsigned* __restrict__ cnt) {
  __shared__ __align__(16) char smem[SM_SIZE];
  if (blockIdx.x < NLSTM)
    lstm_role(Whh16, XG2, h0f, HS, bar, smem);
  worker_role(HS, Wout16, b_out, out, bar, cnt, smem);
}

extern "C" void kernel_launch(void* const* d_in, const int* in_sizes, int n_in,
                              void* d_out, int out_size, void* d_ws, size_t ws_size,
                              hipStream_t stream) {
  const float* z     = (const float*)d_in[0];
  const int*   x     = (const int*)d_in[1];
  const float* W_h   = (const float*)d_in[2];
  const float* b_h   = (const float*)d_in[3];
  const float* emb   = (const float*)d_in[4];
  const float* W_ih  = (const float*)d_in[5];
  const float* W_hh  = (const float*)d_in[6];
  const float* b_ih  = (const float*)d_in[7];
  const float* b_hh  = (const float*)d_in[8];
  const float* W_out = (const float*)d_in[9];
  const float* b_out = (const float*)d_in[10];
  float* out = (float*)d_out;

  char* ws = (char*)d_ws;
  size_t off = 0;
  auto carve = [&](size_t n) { char* p = ws + off; off += (n + 255) & ~(size_t)255; return p; };
  f16*   E16    = (f16*)carve((size_t)BT * DE * 2);     // 4 MB
  f16*   Wih16  = (f16*)carve((size_t)G4 * DE * 2);     // 4 MB
  f16*   Whh16  = (f16*)carve((size_t)G4 * HID * 2);    // 8 MB
  f16*   Wout16 = (f16*)carve((size_t)VOC * HID * 2);   // 64 MB
  float* XG2    = (float*)carve((size_t)BT * G4 * 4);   // 64 MB, [g][b][t]
  f16*   HS     = (f16*)carve((size_t)BT * HID * 2);    // 8 MB, t-major rows
  f16*   h0f    = (f16*)carve((size_t)Bb * HID * 2);
  float* bs     = (float*)carve((size_t)G4 * 4);
  unsigned* bar = (unsigned*)carve(256);
  unsigned* cnt = (unsigned*)carve(256);

  (void)hipMemsetAsync(bar, 0, 256, stream);   // reset flags each call
  (void)hipMemsetAsync(cnt, 0, 256, stream);   // reset tile queue each call

  cvt_kernel<<<2048, 256, 0, stream>>>(W_ih,  Wih16,  G4 * DE / 4);
  cvt_kernel<<<2048, 256, 0, stream>>>(W_hh,  Whh16,  G4 * HID / 4);
  cvt_kernel<<<2048, 256, 0, stream>>>(W_out, Wout16, VOC * HID / 4);
  gather_kernel<<<BT * DE / 8 / 256, 256, 0, stream>>>(emb, x, E16);
  bsum_kernel<<<16, 256, 0, stream>>>(b_ih, b_hh, bs, G4);
  h0_kernel<<<128, 256, 0, stream>>>(z, W_h, b_h, h0f);

  dim3 g1(G4 / 128, BT / 128);     // 32 x 32
  gemmxg_kernel<<<g1, 256, 0, stream>>>(E16, Wih16, bs, XG2, BT, G4, DE);

  fused_kernel<<<256, 512, 0, stream>>>(Whh16, XG2, h0f, HS, Wout16, b_out, out, bar, cnt);
}

// Round 14
// 1016.916 us; speedup vs baseline: 1.4397x; 1.0210x over previous
//
#include <hip/hip_runtime.h>

typedef _Float16 f16;
typedef _Float16 f16x8 __attribute__((ext_vector_type(8)));
typedef _Float16 f16x4 __attribute__((ext_vector_type(4)));
typedef float    f32x4 __attribute__((ext_vector_type(4)));
typedef unsigned long long ull;

static constexpr int Bb  = 32;
static constexpr int Tt  = 128;
static constexpr int HID = 1024;
static constexpr int ZD  = 256;
static constexpr int DE  = 512;
static constexpr int VOC = 32000;
static constexpr int BT  = Bb * Tt;   // 4096
static constexpr int G4  = 4 * HID;   // 4096
static constexpr int NLSTM = 64;      // lstm-role blocks (16 hidden units each)
static constexpr int NTILES = (BT / 256) * (VOC / 256);  // 16 * 125 = 2000
// HS layout is T-MAJOR: row m' = t*32 + b, so a 256-row GEMM M-tile = 8 steps.
// HS WRITES are agent-scope (visible at IF); ALL reads are flag-gated after the
// writes, so normal cached loads are safe (each XCD L2 fills each line once).

// ---- async global->LDS, 16B per lane; LDS dest = wave-uniform base + lane*16 ----
__device__ __forceinline__ void gld_lds16(const void* g, void* l) {
  __builtin_amdgcn_global_load_lds((const __attribute__((address_space(1))) unsigned int*)g,
                                   (__attribute__((address_space(3))) unsigned int*)l,
                                   16, 0, 0);
}

// ---------------- f32 -> f16 convert (vectorized) ----------------
__global__ void cvt_kernel(const float* __restrict__ s, f16* __restrict__ d, int n4) {
  int i = blockIdx.x * blockDim.x + threadIdx.x;
  int st = gridDim.x * blockDim.x;
  for (; i < n4; i += st) {
    float4 v = ((const float4*)s)[i];
    f16x4 o = { (f16)v.x, (f16)v.y, (f16)v.z, (f16)v.w };
    ((f16x4*)d)[i] = o;
  }
}

// ---------------- embedding gather -> f16 ----------------
__global__ void gather_kernel(const float* __restrict__ emb, const int* __restrict__ x,
                              f16* __restrict__ E) {
  int g = blockIdx.x * 256 + threadIdx.x;   // BT*DE/8 threads
  int m = g >> 6, seg = (g & 63) * 8;
  int idx = x[m];
  const float* src = emb + (size_t)idx * DE + seg;
  float4 a = *(const float4*)src;
  float4 b = *(const float4*)(src + 4);
  f16x8 o = { (f16)a.x,(f16)a.y,(f16)a.z,(f16)a.w,(f16)b.x,(f16)b.y,(f16)b.z,(f16)b.w };
  *(f16x8*)(E + (size_t)m * DE + seg) = o;
}

// ---------------- bias sum ----------------
__global__ void bsum_kernel(const float* __restrict__ a, const float* __restrict__ b,
                            float* __restrict__ o, int n) {
  int i = blockIdx.x * blockDim.x + threadIdx.x;
  if (i < n) o[i] = a[i] + b[i];
}

// ---------------- h0 = tanh(z @ W_h^T + b_h), store f16 ----------------
__global__ __launch_bounds__(256) void h0_kernel(const float* __restrict__ z,
                                                 const float* __restrict__ W_h,
                                                 const float* __restrict__ b_h,
                                                 f16* __restrict__ h0f) {
  __shared__ float zs[32][260];
  __shared__ float wsl[8][260];
  const int jc = blockIdx.x, tid = threadIdx.x;
  #pragma unroll
  for (int it = 0; it < 8; ++it) {
    int idx = it * 256 + tid;
    float4 v = ((const float4*)z)[idx];
    int b = idx >> 6, k = (idx & 63) * 4;
    zs[b][k] = v.x; zs[b][k+1] = v.y; zs[b][k+2] = v.z; zs[b][k+3] = v.w;
  }
  #pragma unroll
  for (int it = 0; it < 2; ++it) {
    int idx = it * 256 + tid;
    float4 v = ((const float4*)(W_h + (size_t)jc * 8 * ZD))[idx];
    int r = idx >> 6, k = (idx & 63) * 4;
    wsl[r][k] = v.x; wsl[r][k+1] = v.y; wsl[r][k+2] = v.z; wsl[r][k+3] = v.w;
  }
  __syncthreads();
  const int b = tid >> 3, jj = tid & 7;
  const int j = jc * 8 + jj;
  float acc = b_h[j];
  for (int k = 0; k < ZD; ++k) acc += zs[b][k] * wsl[jj][k];
  h0f[(size_t)b * HID + j] = (f16)tanhf(acc);
}

// ---------------- GEMM 128x128 (proven): C = A @ B^T + bias, XG output layout ---
__global__ __launch_bounds__(256, 2) void gemmxg_kernel(
    const f16* __restrict__ A, const f16* __restrict__ B,
    const float* __restrict__ bias, float* __restrict__ C,
    int M, int N, int K) {
  __shared__ f16 As[128 * 64];
  __shared__ f16 Bs[128 * 64];
  const int n0 = blockIdx.x * 128, m0 = blockIdx.y * 128;
  const int tid = threadIdx.x, wid = tid >> 6, lane = tid & 63;
  const int wm = wid >> 1, wn = wid & 1;
  const int sr = lane >> 3, sk = (lane & 7) * 8;
  f32x4 acc[4][4] = {};
  for (int k0 = 0; k0 < K; k0 += 64) {
    __syncthreads();
    #pragma unroll
    for (int i = 0; i < 4; ++i) {
      int rr = (wid * 4 + i) * 8;
      gld_lds16(A + (size_t)(m0 + rr + sr) * K + k0 + sk, &As[rr * 64]);
      gld_lds16(B + (size_t)(n0 + rr + sr) * K + k0 + sk, &Bs[rr * 64]);
    }
    __syncthreads();
    #pragma unroll
    for (int ks = 0; ks < 2; ++ks) {
      f16x8 af[4], bf[4];
      #pragma unroll
      for (int mt = 0; mt < 4; ++mt)
        af[mt] = *(const f16x8*)&As[(wm * 64 + mt * 16 + (lane & 15)) * 64 + ks * 32 + (lane >> 4) * 8];
      #pragma unroll
      for (int nt = 0; nt < 4; ++nt)
        bf[nt] = *(const f16x8*)&Bs[(wn * 64 + nt * 16 + (lane & 15)) * 64 + ks * 32 + (lane >> 4) * 8];
      #pragma unroll
      for (int mt = 0; mt < 4; ++mt)
        #pragma unroll
        for (int nt = 0; nt < 4; ++nt)
          acc[mt][nt] = __builtin_amdgcn_mfma_f32_16x16x32_f16(af[mt], bf[nt], acc[mt][nt], 0, 0, 0);
    }
  }
  #pragma unroll
  for (int nt = 0; nt < 4; ++nt) {
    int col = n0 + wn * 64 + nt * 16 + (lane & 15);
    float bv = bias[col];
    #pragma unroll
    for (int mt = 0; mt < 4; ++mt) {
      int row = m0 + wm * 64 + mt * 16 + (lane >> 4) * 4;
      int b = row >> 7, t0 = row & 127;
      float4 v = { acc[mt][nt][0] + bv, acc[mt][nt][1] + bv,
                   acc[mt][nt][2] + bv, acc[mt][nt][3] + bv };
      *(float4*)&C[((size_t)col * 32 + b) * 128 + t0] = v;
    }
  }
}

// =================================================================================
// FUSED persistent kernel: 256 blocks x 512 threads, 1 block/CU (capacity-resident).
//   blocks 0..63 : LSTM recurrence role (t-major HS), then join worker pool.
//   blocks 64..255: GEMM workers from the start.
// Workers pull 256x256 output tiles (mg-major => ascending t) from an atomic queue,
// wait on readiness flags with s_sleep backoff, then run the 4-buf counted-vmcnt
// ring GEMM (T3+T4+T5+T2). A (HS) and B (Wout16) both via global_load_lds with
// pre-swizzled source cols; HS reads are NORMAL loads (L2-cached; flag-gating makes
// them coherent - see header note).
// =================================================================================
static constexpr int SM_HL   = 0;                       // f16 hl[32][1032] = 66048 B
static constexpr int SM_PART = 66048;                   // float part[8][64][33] = 67584 B
static constexpr int SM_IDX  = 133632;                  // unsigned sIdx
static constexpr int SM_SIZE = 133648;

__device__ void lstm_role(const f16* __restrict__ Whh16, const float* __restrict__ XG2,
                          const f16* __restrict__ h0f, f16* __restrict__ HS,
                          unsigned* __restrict__ bar, char* smem) {
  const int bid = blockIdx.x, tid = threadIdx.x;
  const int lane = tid & 63, wid = tid >> 6;
  const int lr = lane & 15, hi = lane >> 4;
  const int j0 = bid * 16;
  f16 (*hl)[1032] = (f16 (*)[1032])(smem + SM_HL);
  float (*part)[64][33] = (float (*)[64][33])(smem + SM_PART);

  f16x8 wfrag[4][4];
  #pragma unroll
  for (int rt = 0; rt < 4; ++rt) {
    int g = rt * HID + j0 + lr;
    #pragma unroll
    for (int kk = 0; kk < 4; ++kk)
      wfrag[rt][kk] = *(const f16x8*)(Whh16 + (size_t)g * HID + wid * 128 + kk * 32 + hi * 8);
  }

  const int ub = tid & 15, bb = tid >> 4;
  float creg = 0.f;

  for (int t = 0; t < Tt; ++t) {
    float xg[4];
    #pragma unroll
    for (int q = 0; q < 4; ++q)
      xg[q] = XG2[((size_t)(q * HID + j0 + ub) * 32 + bb) * 128 + t];

    if (t > 0) {
      if (wid == 0) {
        const unsigned tgt = (unsigned)t;
        for (;;) {
          unsigned f = __hip_atomic_load(&bar[lane], __ATOMIC_RELAXED, __HIP_MEMORY_SCOPE_AGENT);
          if (__all(f >= tgt)) break;
        }
      }
      __syncthreads();
    }

    // stage h_{t-1}: wave wid loads batch rows 4*wid..+4 (NORMAL 8B loads, t-major)
    {
      ull tmp[4][4];
      #pragma unroll
      for (int r = 0; r < 4; ++r) {
        int row = wid * 4 + r;
        const f16* hb = (t == 0) ? (h0f + (size_t)row * HID)
                                 : (HS + (size_t)((t - 1) * 32 + row) * HID);
        #pragma unroll
        for (int c = 0; c < 4; ++c)
          tmp[r][c] = ((const ull*)hb)[c * 64 + lane];
      }
      #pragma unroll
      for (int r = 0; r < 4; ++r) {
        int row = wid * 4 + r;
        #pragma unroll
        for (int c = 0; c < 4; ++c)
          *(ull*)&hl[row][(c * 64 + lane) * 4] = tmp[r][c];
      }
    }
    __syncthreads();

    // gate MFMA: C[64 gate rows][32 batches], this wave's k-eighth
    {
      f32x4 acc[4][2] = {};
      #pragma unroll
      for (int kk = 0; kk < 4; ++kk) {
        int ko = wid * 128 + kk * 32 + hi * 8;
        f16x8 bf0 = *(const f16x8*)&hl[lr][ko];
        f16x8 bf1 = *(const f16x8*)&hl[16 + lr][ko];
        #pragma unroll
        for (int rt = 0; rt < 4; ++rt) {
          acc[rt][0] = __builtin_amdgcn_mfma_f32_16x16x32_f16(wfrag[rt][kk], bf0, acc[rt][0], 0, 0, 0);
          acc[rt][1] = __builtin_amdgcn_mfma_f32_16x16x32_f16(wfrag[rt][kk], bf1, acc[rt][1], 0, 0, 0);
        }
      }
      #pragma unroll
      for (int rt = 0; rt < 4; ++rt)
        #pragma unroll
        for (int bt = 0; bt < 2; ++bt)
          #pragma unroll
          for (int p = 0; p < 4; ++p)
            part[wid][rt * 16 + hi * 4 + p][bt * 16 + lr] = acc[rt][bt][p];
    }
    __syncthreads();

    // LSTM update: thread (ub, bb); h store agent-coherent 2B, t-major row
    {
      float g4[4];
      #pragma unroll
      for (int q = 0; q < 4; ++q) {
        int i = q * 16 + ub;
        float s = xg[q];
        #pragma unroll
        for (int w = 0; w < 8; ++w) s += part[w][i][bb];
        g4[q] = s;
      }
      float ig = 1.f / (1.f + __expf(-g4[0]));
      float fg = 1.f / (1.f + __expf(-g4[1]));
      float gg = tanhf(g4[2]);
      float og = 1.f / (1.f + __expf(-g4[3]));
      creg = fg * creg + ig * gg;
      float h = og * tanhf(creg);
      union { f16 h; unsigned short u; } cv;
      cv.h = (f16)h;
      __hip_atomic_store((unsigned short*)&HS[(size_t)(t * 32 + bb) * HID + j0 + ub],
                         cv.u, __ATOMIC_RELAXED, __HIP_MEMORY_SCOPE_AGENT);
    }

    // post completion flag for EVERY t (workers need t=127 too)
    asm volatile("s_waitcnt vmcnt(0)" ::: "memory");
    __syncthreads();
    if (tid == 0)
      __hip_atomic_store(&bar[bid], (unsigned)(t + 1),
                         __ATOMIC_RELAXED, __HIP_MEMORY_SCOPE_AGENT);
  }
}

__device__ void worker_role(const f16* __restrict__ HS, const f16* __restrict__ Wout16,
                            const float* __restrict__ b_out, float* __restrict__ out,
                            unsigned* __restrict__ bar, unsigned* __restrict__ cnt,
                            char* smem) {
  const int tid = threadIdx.x, wid = tid >> 6, lane = tid & 63;
  const int wm = wid >> 2, wn = wid & 3;
  const int lr = lane & 15, hi = lane >> 4;
  const int srow = lane >> 2;
  const int scol = ((lane & 3) ^ ((lane >> 3) & 3)) * 8;   // pre-swizzled source col
  const int sx   = (hi ^ ((lr >> 1) & 3)) * 8;             // swizzled read slot
  f16* As = (f16*)(smem);            // [4][8192] halves = 65536 B
  f16* Bs = (f16*)(smem + 65536);    // [4][8192]
  unsigned* sIdx = (unsigned*)(smem + SM_IDX);
  const int cb0 = wid * 2, cb1 = wid * 2 + 1;

  for (;;) {
    if (tid == 0) *sIdx = atomicAdd(cnt, 1u);
    __syncthreads();
    unsigned idx = *sIdx;
    if (idx >= (unsigned)NTILES) break;
    int mg = idx / 125, ng = idx - mg * 125;
    // readiness: all 64 lstm blocks completed step 8*mg+7 (flag >= 8mg+8)
    if (wid == 0) {
      const unsigned tgt = (unsigned)(8 * mg + 8);
      for (;;) {
        unsigned f = __hip_atomic_load(&bar[lane], __ATOMIC_RELAXED, __HIP_MEMORY_SCOPE_AGENT);
        if (__all(f >= tgt)) break;
        __builtin_amdgcn_s_sleep(32);
      }
    }
    __syncthreads();

    const int m0 = mg * 256, n0 = ng * 256;
    f32x4 acc[8][4] = {};

    auto STAGE = [&](int kt) {
      const int k0 = kt << 5, buf = kt & 3;
      gld_lds16(HS     + (size_t)(m0 + cb0 * 16 + srow) * HID + k0 + scol, As + buf * 8192 + cb0 * 512);
      gld_lds16(Wout16 + (size_t)(n0 + cb0 * 16 + srow) * HID + k0 + scol, Bs + buf * 8192 + cb0 * 512);
      gld_lds16(HS     + (size_t)(m0 + cb1 * 16 + srow) * HID + k0 + scol, As + buf * 8192 + cb1 * 512);
      gld_lds16(Wout16 + (size_t)(n0 + cb1 * 16 + srow) * HID + k0 + scol, Bs + buf * 8192 + cb1 * 512);
    };

    STAGE(0); STAGE(1); STAGE(2);
    for (int kt = 0; kt < 32; ++kt) {
      if (kt < 30)       asm volatile("s_waitcnt vmcnt(8)" ::: "memory");
      else if (kt == 30) asm volatile("s_waitcnt vmcnt(4)" ::: "memory");
      else               asm volatile("s_waitcnt vmcnt(0)" ::: "memory");
      __builtin_amdgcn_s_barrier();
      if (kt + 3 < 32) STAGE(kt + 3);
      const f16* as = As + (kt & 3) * 8192;
      const f16* bs = Bs + (kt & 3) * 8192;
      f16x8 af[8], bf[4];
      #pragma unroll
      for (int mt = 0; mt < 8; ++mt)
        af[mt] = *(const f16x8*)&as[(wm * 128 + mt * 16 + lr) * 32 + sx];
      #pragma unroll
      for (int nt = 0; nt < 4; ++nt)
        bf[nt] = *(const f16x8*)&bs[(wn * 64 + nt * 16 + lr) * 32 + sx];
      __builtin_amdgcn_s_setprio(1);
      #pragma unroll
      for (int mt = 0; mt < 8; ++mt)
        #pragma unroll
        for (int nt = 0; nt < 4; ++nt)
          acc[mt][nt] = __builtin_amdgcn_mfma_f32_16x16x32_f16(af[mt], bf[nt], acc[mt][nt], 0, 0, 0);
      __builtin_amdgcn_s_setprio(0);
    }

    // epilogue: un-permute rows (m' = t*32+b -> out row b*128+t), add bias
    #pragma unroll
    for (int nt = 0; nt < 4; ++nt) {
      int col = n0 + wn * 64 + nt * 16 + lr;
      float bv = b_out[col];
      #pragma unroll
      for (int mt = 0; mt < 8; ++mt) {
        int mbase = m0 + wm * 128 + mt * 16 + hi * 4;
        #pragma unroll
        for (int p = 0; p < 4; ++p) {
          int mp = mbase + p;
          int orow = (mp & 31) * 128 + (mp >> 5);
          out[(size_t)orow * VOC + col] = acc[mt][nt][p] + bv;
        }
      }
    }
    __syncthreads();   // all frag reads done before next tile's STAGE overwrites LDS
  }
}

__global__ __launch_bounds__(512, 1) void fused_kernel(
    const f16* __restrict__ Whh16, const float* __restrict__ XG2,
    const f16* __restrict__ h0f, f16* __restrict__ HS,
    const f16* __restrict__ Wout16, const float* __restrict__ b_out,
    float* __restrict__ out, unsigned* __restrict__ bar, unsigned* __restrict__ cnt) {
  __shared__ __align__(16) char smem[SM_SIZE];
  if (blockIdx.x < NLSTM)
    lstm_role(Whh16, XG2, h0f, HS, bar, smem);
  worker_role(HS, Wout16, b_out, out, bar, cnt, smem);
}

extern "C" void kernel_launch(void* const* d_in, const int* in_sizes, int n_in,
                              void* d_out, int out_size, void* d_ws, size_t ws_size,
                              hipStream_t stream) {
  const float* z     = (const float*)d_in[0];
  const int*   x     = (const int*)d_in[1];
  const float* W_h   = (const float*)d_in[2];
  const float* b_h   = (const float*)d_in[3];
  const float* emb   = (const float*)d_in[4];
  const float* W_ih  = (const float*)d_in[5];
  const float* W_hh  = (const float*)d_in[6];
  const float* b_ih  = (const float*)d_in[7];
  const float* b_hh  = (const float*)d_in[8];
  const float* W_out = (const float*)d_in[9];
  const float* b_out = (const float*)d_in[10];
  float* out = (float*)d_out;

  char* ws = (char*)d_ws;
  size_t off = 0;
  auto carve = [&](size_t n) { char* p = ws + off; off += (n + 255) & ~(size_t)255; return p; };
  f16*   E16    = (f16*)carve((size_t)BT * DE * 2);     // 4 MB
  f16*   Wih16  = (f16*)carve((size_t)G4 * DE * 2);     // 4 MB
  f16*   Whh16  = (f16*)carve((size_t)G4 * HID * 2);    // 8 MB
  f16*   Wout16 = (f16*)carve((size_t)VOC * HID * 2);   // 64 MB
  float* XG2    = (float*)carve((size_t)BT * G4 * 4);   // 64 MB, [g][b][t]
  f16*   HS     = (f16*)carve((size_t)BT * HID * 2);    // 8 MB, t-major rows
  f16*   h0f    = (f16*)carve((size_t)Bb * HID * 2);
  float* bs     = (float*)carve((size_t)G4 * 4);
  unsigned* bar = (unsigned*)carve(256);
  unsigned* cnt = (unsigned*)carve(256);

  (void)hipMemsetAsync(bar, 0, 256, stream);   // reset flags each call
  (void)hipMemsetAsync(cnt, 0, 256, stream);   // reset tile queue each call

  cvt_kernel<<<2048, 256, 0, stream>>>(W_ih,  Wih16,  G4 * DE / 4);
  cvt_kernel<<<2048, 256, 0, stream>>>(W_hh,  Whh16,  G4 * HID / 4);
  cvt_kernel<<<2048, 256, 0, stream>>>(W_out, Wout16, VOC * HID / 4);
  gather_kernel<<<BT * DE / 8 / 256, 256, 0, stream>>>(emb, x, E16);
  bsum_kernel<<<16, 256, 0, stream>>>(b_ih, b_hh, bs, G4);
  h0_kernel<<<128, 256, 0, stream>>>(z, W_h, b_h, h0f);

  dim3 g1(G4 / 128, BT / 128);     // 32 x 32
  gemmxg_kernel<<<g1, 256, 0, stream>>>(E16, Wih16, bs, XG2, BT, G4, DE);

  fused_kernel<<<256, 512, 0, stream>>>(Whh16, XG2, h0f, HS, Wout16, b_out, out, bar, cnt);
}

// Round 15
// 933.136 us; speedup vs baseline: 1.5689x; 1.0898x over previous
//
#include <hip/hip_runtime.h>

typedef _Float16 f16;
typedef _Float16 f16x8 __attribute__((ext_vector_type(8)));
typedef _Float16 f16x4 __attribute__((ext_vector_type(4)));
typedef float    f32x4 __attribute__((ext_vector_type(4)));
typedef unsigned long long ull;

static constexpr int Bb  = 32;
static constexpr int Tt  = 128;
static constexpr int HID = 1024;
static constexpr int ZD  = 256;
static constexpr int DE  = 512;
static constexpr int VOC = 32000;
static constexpr int BT  = Bb * Tt;   // 4096
static constexpr int G4  = 4 * HID;   // 4096
static constexpr int NLSTM = 64;      // lstm-role blocks (16 hidden units each)
static constexpr int NTILES = (BT / 256) * (VOC / 256);  // 16 * 125 = 2000
// HS layout is T-MAJOR: row m' = t*32 + b, so a 256-row GEMM M-tile = 8 steps.
// Workers poll ONE aggregated word (gready, posted by lstm block 0) instead of
// the 64 per-block flag lines -> the lstm exchange's flag lines see no worker
// read storm.

// ---- async global->LDS, 16B per lane; LDS dest = wave-uniform base + lane*16 ----
__device__ __forceinline__ void gld_lds16(const void* g, void* l) {
  __builtin_amdgcn_global_load_lds((const __attribute__((address_space(1))) unsigned int*)g,
                                   (__attribute__((address_space(3))) unsigned int*)l,
                                   16, 0, 0);
}

// ---------------- f32 -> f16 convert (vectorized) ----------------
__global__ void cvt_kernel(const float* __restrict__ s, f16* __restrict__ d, int n4) {
  int i = blockIdx.x * blockDim.x + threadIdx.x;
  int st = gridDim.x * blockDim.x;
  for (; i < n4; i += st) {
    float4 v = ((const float4*)s)[i];
    f16x4 o = { (f16)v.x, (f16)v.y, (f16)v.z, (f16)v.w };
    ((f16x4*)d)[i] = o;
  }
}

// ---------------- embedding gather -> f16 ----------------
__global__ void gather_kernel(const float* __restrict__ emb, const int* __restrict__ x,
                              f16* __restrict__ E) {
  int g = blockIdx.x * 256 + threadIdx.x;   // BT*DE/8 threads
  int m = g >> 6, seg = (g & 63) * 8;
  int idx = x[m];
  const float* src = emb + (size_t)idx * DE + seg;
  float4 a = *(const float4*)src;
  float4 b = *(const float4*)(src + 4);
  f16x8 o = { (f16)a.x,(f16)a.y,(f16)a.z,(f16)a.w,(f16)b.x,(f16)b.y,(f16)b.z,(f16)b.w };
  *(f16x8*)(E + (size_t)m * DE + seg) = o;
}

// ---------------- bias sum ----------------
__global__ void bsum_kernel(const float* __restrict__ a, const float* __restrict__ b,
                            float* __restrict__ o, int n) {
  int i = blockIdx.x * blockDim.x + threadIdx.x;
  if (i < n) o[i] = a[i] + b[i];
}

// ---------------- h0 = tanh(z @ W_h^T + b_h), store f16 ----------------
__global__ __launch_bounds__(256) void h0_kernel(const float* __restrict__ z,
                                                 const float* __restrict__ W_h,
                                                 const float* __restrict__ b_h,
                                                 f16* __restrict__ h0f) {
  __shared__ float zs[32][260];
  __shared__ float wsl[8][260];
  const int jc = blockIdx.x, tid = threadIdx.x;
  #pragma unroll
  for (int it = 0; it < 8; ++it) {
    int idx = it * 256 + tid;
    float4 v = ((const float4*)z)[idx];
    int b = idx >> 6, k = (idx & 63) * 4;
    zs[b][k] = v.x; zs[b][k+1] = v.y; zs[b][k+2] = v.z; zs[b][k+3] = v.w;
  }
  #pragma unroll
  for (int it = 0; it < 2; ++it) {
    int idx = it * 256 + tid;
    float4 v = ((const float4*)(W_h + (size_t)jc * 8 * ZD))[idx];
    int r = idx >> 6, k = (idx & 63) * 4;
    wsl[r][k] = v.x; wsl[r][k+1] = v.y; wsl[r][k+2] = v.z; wsl[r][k+3] = v.w;
  }
  __syncthreads();
  const int b = tid >> 3, jj = tid & 7;
  const int j = jc * 8 + jj;
  float acc = b_h[j];
  for (int k = 0; k < ZD; ++k) acc += zs[b][k] * wsl[jj][k];
  h0f[(size_t)b * HID + j] = (f16)tanhf(acc);
}

// ---------------- GEMM 128x128 (proven): C = A @ B^T + bias, XG output layout ---
__global__ __launch_bounds__(256, 2) void gemmxg_kernel(
    const f16* __restrict__ A, const f16* __restrict__ B,
    const float* __restrict__ bias, float* __restrict__ C,
    int M, int N, int K) {
  __shared__ f16 As[128 * 64];
  __shared__ f16 Bs[128 * 64];
  const int n0 = blockIdx.x * 128, m0 = blockIdx.y * 128;
  const int tid = threadIdx.x, wid = tid >> 6, lane = tid & 63;
  const int wm = wid >> 1, wn = wid & 1;
  const int sr = lane >> 3, sk = (lane & 7) * 8;
  f32x4 acc[4][4] = {};
  for (int k0 = 0; k0 < K; k0 += 64) {
    __syncthreads();
    #pragma unroll
    for (int i = 0; i < 4; ++i) {
      int rr = (wid * 4 + i) * 8;
      gld_lds16(A + (size_t)(m0 + rr + sr) * K + k0 + sk, &As[rr * 64]);
      gld_lds16(B + (size_t)(n0 + rr + sr) * K + k0 + sk, &Bs[rr * 64]);
    }
    __syncthreads();
    #pragma unroll
    for (int ks = 0; ks < 2; ++ks) {
      f16x8 af[4], bf[4];
      #pragma unroll
      for (int mt = 0; mt < 4; ++mt)
        af[mt] = *(const f16x8*)&As[(wm * 64 + mt * 16 + (lane & 15)) * 64 + ks * 32 + (lane >> 4) * 8];
      #pragma unroll
      for (int nt = 0; nt < 4; ++nt)
        bf[nt] = *(const f16x8*)&Bs[(wn * 64 + nt * 16 + (lane & 15)) * 64 + ks * 32 + (lane >> 4) * 8];
      #pragma unroll
      for (int mt = 0; mt < 4; ++mt)
        #pragma unroll
        for (int nt = 0; nt < 4; ++nt)
          acc[mt][nt] = __builtin_amdgcn_mfma_f32_16x16x32_f16(af[mt], bf[nt], acc[mt][nt], 0, 0, 0);
    }
  }
  #pragma unroll
  for (int nt = 0; nt < 4; ++nt) {
    int col = n0 + wn * 64 + nt * 16 + (lane & 15);
    float bv = bias[col];
    #pragma unroll
    for (int mt = 0; mt < 4; ++mt) {
      int row = m0 + wm * 64 + mt * 16 + (lane >> 4) * 4;
      int b = row >> 7, t0 = row & 127;
      float4 v = { acc[mt][nt][0] + bv, acc[mt][nt][1] + bv,
                   acc[mt][nt][2] + bv, acc[mt][nt][3] + bv };
      *(float4*)&C[((size_t)col * 32 + b) * 128 + t0] = v;
    }
  }
}

// =================================================================================
// FUSED persistent kernel: 256 blocks x 512 threads, 1 block/CU (capacity-resident).
//   blocks 0..63 : LSTM recurrence role (t-major HS), then join worker pool.
//   blocks 64..255: GEMM workers from the start.
// Block 0 aggregates lstm progress into ONE word (gready); workers poll only that
// word -> no reader storm on the lstm flag lines.
// =================================================================================
static constexpr int SM_HL   = 0;                       // f16 hl[32][1032] = 66048 B
static constexpr int SM_PART = 66048;                   // float part[8][64][33] = 67584 B
static constexpr int SM_IDX  = 133632;                  // unsigned sIdx
static constexpr int SM_SIZE = 133648;

__device__ void lstm_role(const f16* __restrict__ Whh16, const float* __restrict__ XG2,
                          const f16* __restrict__ h0f, f16* __restrict__ HS,
                          unsigned* __restrict__ bar, unsigned* __restrict__ gready,
                          char* smem) {
  const int bid = blockIdx.x, tid = threadIdx.x;
  const int lane = tid & 63, wid = tid >> 6;
  const int lr = lane & 15, hi = lane >> 4;
  const int j0 = bid * 16;
  f16 (*hl)[1032] = (f16 (*)[1032])(smem + SM_HL);
  float (*part)[64][33] = (float (*)[64][33])(smem + SM_PART);

  f16x8 wfrag[4][4];
  #pragma unroll
  for (int rt = 0; rt < 4; ++rt) {
    int g = rt * HID + j0 + lr;
    #pragma unroll
    for (int kk = 0; kk < 4; ++kk)
      wfrag[rt][kk] = *(const f16x8*)(Whh16 + (size_t)g * HID + wid * 128 + kk * 32 + hi * 8);
  }

  const int ub = tid & 15, bb = tid >> 4;
  float creg = 0.f;

  for (int t = 0; t < Tt; ++t) {
    float xg[4];
    #pragma unroll
    for (int q = 0; q < 4; ++q)
      xg[q] = XG2[((size_t)(q * HID + j0 + ub) * 32 + bb) * 128 + t];

    if (t > 0) {
      if (wid == 0) {
        const unsigned tgt = (unsigned)t;
        for (;;) {
          unsigned f = __hip_atomic_load(&bar[lane], __ATOMIC_RELAXED, __HIP_MEMORY_SCOPE_AGENT);
          if (__all(f >= tgt)) break;
        }
        // block 0 aggregates progress for the workers (single word, other line)
        if (bid == 0 && lane == 0)
          __hip_atomic_store(gready, (unsigned)t, __ATOMIC_RELAXED, __HIP_MEMORY_SCOPE_AGENT);
      }
      __syncthreads();
    }

    // stage h_{t-1}: wave wid loads batch rows 4*wid..+4 (NORMAL 8B loads, t-major)
    {
      ull tmp[4][4];
      #pragma unroll
      for (int r = 0; r < 4; ++r) {
        int row = wid * 4 + r;
        const f16* hb = (t == 0) ? (h0f + (size_t)row * HID)
                                 : (HS + (size_t)((t - 1) * 32 + row) * HID);
        #pragma unroll
        for (int c = 0; c < 4; ++c)
          tmp[r][c] = ((const ull*)hb)[c * 64 + lane];
      }
      #pragma unroll
      for (int r = 0; r < 4; ++r) {
        int row = wid * 4 + r;
        #pragma unroll
        for (int c = 0; c < 4; ++c)
          *(ull*)&hl[row][(c * 64 + lane) * 4] = tmp[r][c];
      }
    }
    __syncthreads();

    // gate MFMA: C[64 gate rows][32 batches], this wave's k-eighth
    {
      f32x4 acc[4][2] = {};
      #pragma unroll
      for (int kk = 0; kk < 4; ++kk) {
        int ko = wid * 128 + kk * 32 + hi * 8;
        f16x8 bf0 = *(const f16x8*)&hl[lr][ko];
        f16x8 bf1 = *(const f16x8*)&hl[16 + lr][ko];
        #pragma unroll
        for (int rt = 0; rt < 4; ++rt) {
          acc[rt][0] = __builtin_amdgcn_mfma_f32_16x16x32_f16(wfrag[rt][kk], bf0, acc[rt][0], 0, 0, 0);
          acc[rt][1] = __builtin_amdgcn_mfma_f32_16x16x32_f16(wfrag[rt][kk], bf1, acc[rt][1], 0, 0, 0);
        }
      }
      #pragma unroll
      for (int rt = 0; rt < 4; ++rt)
        #pragma unroll
        for (int bt = 0; bt < 2; ++bt)
          #pragma unroll
          for (int p = 0; p < 4; ++p)
            part[wid][rt * 16 + hi * 4 + p][bt * 16 + lr] = acc[rt][bt][p];
    }
    __syncthreads();

    // LSTM update: thread (ub, bb); h store agent-coherent 2B, t-major row
    {
      float g4[4];
      #pragma unroll
      for (int q = 0; q < 4; ++q) {
        int i = q * 16 + ub;
        float s = xg[q];
        #pragma unroll
        for (int w = 0; w < 8; ++w) s += part[w][i][bb];
        g4[q] = s;
      }
      float ig = 1.f / (1.f + __expf(-g4[0]));
      float fg = 1.f / (1.f + __expf(-g4[1]));
      float gg = tanhf(g4[2]);
      float og = 1.f / (1.f + __expf(-g4[3]));
      creg = fg * creg + ig * gg;
      float h = og * tanhf(creg);
      union { f16 h; unsigned short u; } cv;
      cv.h = (f16)h;
      __hip_atomic_store((unsigned short*)&HS[(size_t)(t * 32 + bb) * HID + j0 + ub],
                         cv.u, __ATOMIC_RELAXED, __HIP_MEMORY_SCOPE_AGENT);
    }

    // post completion flag for EVERY t (block 0 aggregates; workers never read bar)
    asm volatile("s_waitcnt vmcnt(0)" ::: "memory");
    __syncthreads();
    if (tid == 0)
      __hip_atomic_store(&bar[bid], (unsigned)(t + 1),
                         __ATOMIC_RELAXED, __HIP_MEMORY_SCOPE_AGENT);
  }

  // block 0: final aggregation (flags reach 128 only after all finish t=127)
  if (bid == 0) {
    if (wid == 0) {
      for (;;) {
        unsigned f = __hip_atomic_load(&bar[lane], __ATOMIC_RELAXED, __HIP_MEMORY_SCOPE_AGENT);
        if (__all(f >= (unsigned)Tt)) break;
      }
      if (lane == 0)
        __hip_atomic_store(gready, (unsigned)Tt, __ATOMIC_RELAXED, __HIP_MEMORY_SCOPE_AGENT);
    }
    __syncthreads();
  }
}

__device__ void worker_role(const f16* __restrict__ HS, const f16* __restrict__ Wout16,
                            const float* __restrict__ b_out, float* __restrict__ out,
                            unsigned* __restrict__ gready, unsigned* __restrict__ cnt,
                            char* smem) {
  const int tid = threadIdx.x, wid = tid >> 6, lane = tid & 63;
  const int wm = wid >> 2, wn = wid & 3;
  const int lr = lane & 15, hi = lane >> 4;
  const int srow = lane >> 2;
  const int scol = ((lane & 3) ^ ((lane >> 3) & 3)) * 8;   // pre-swizzled source col
  const int sx   = (hi ^ ((lr >> 1) & 3)) * 8;             // swizzled read slot
  f16* As = (f16*)(smem);            // [4][8192] halves = 65536 B
  f16* Bs = (f16*)(smem + 65536);    // [4][8192]
  unsigned* sIdx = (unsigned*)(smem + SM_IDX);
  const int cb0 = wid * 2, cb1 = wid * 2 + 1;

  for (;;) {
    if (tid == 0) *sIdx = atomicAdd(cnt, 1u);
    __syncthreads();
    unsigned idx = *sIdx;
    if (idx >= (unsigned)NTILES) break;
    int mg = idx / 125, ng = idx - mg * 125;
    // readiness: single aggregated word, s_sleep backoff (no storm on flag lines)
    if (wid == 0) {
      const unsigned tgt = (unsigned)(8 * mg + 8);
      for (;;) {
        unsigned g = __hip_atomic_load(gready, __ATOMIC_RELAXED, __HIP_MEMORY_SCOPE_AGENT);
        if (g >= tgt) break;
        __builtin_amdgcn_s_sleep(64);
      }
    }
    __syncthreads();

    const int m0 = mg * 256, n0 = ng * 256;
    f32x4 acc[8][4] = {};

    auto STAGE = [&](int kt) {
      const int k0 = kt << 5, buf = kt & 3;
      gld_lds16(HS     + (size_t)(m0 + cb0 * 16 + srow) * HID + k0 + scol, As + buf * 8192 + cb0 * 512);
      gld_lds16(Wout16 + (size_t)(n0 + cb0 * 16 + srow) * HID + k0 + scol, Bs + buf * 8192 + cb0 * 512);
      gld_lds16(HS     + (size_t)(m0 + cb1 * 16 + srow) * HID + k0 + scol, As + buf * 8192 + cb1 * 512);
      gld_lds16(Wout16 + (size_t)(n0 + cb1 * 16 + srow) * HID + k0 + scol, Bs + buf * 8192 + cb1 * 512);
    };

    STAGE(0); STAGE(1); STAGE(2);
    for (int kt = 0; kt < 32; ++kt) {
      if (kt < 30)       asm volatile("s_waitcnt vmcnt(8)" ::: "memory");
      else if (kt == 30) asm volatile("s_waitcnt vmcnt(4)" ::: "memory");
      else               asm volatile("s_waitcnt vmcnt(0)" ::: "memory");
      __builtin_amdgcn_s_barrier();
      if (kt + 3 < 32) STAGE(kt + 3);
      const f16* as = As + (kt & 3) * 8192;
      const f16* bs = Bs + (kt & 3) * 8192;
      f16x8 af[8], bf[4];
      #pragma unroll
      for (int mt = 0; mt < 8; ++mt)
        af[mt] = *(const f16x8*)&as[(wm * 128 + mt * 16 + lr) * 32 + sx];
      #pragma unroll
      for (int nt = 0; nt < 4; ++nt)
        bf[nt] = *(const f16x8*)&bs[(wn * 64 + nt * 16 + lr) * 32 + sx];
      __builtin_amdgcn_s_setprio(1);
      #pragma unroll
      for (int mt = 0; mt < 8; ++mt)
        #pragma unroll
        for (int nt = 0; nt < 4; ++nt)
          acc[mt][nt] = __builtin_amdgcn_mfma_f32_16x16x32_f16(af[mt], bf[nt], acc[mt][nt], 0, 0, 0);
      __builtin_amdgcn_s_setprio(0);
    }

    // epilogue: un-permute rows (m' = t*32+b -> out row b*128+t), add bias
    #pragma unroll
    for (int nt = 0; nt < 4; ++nt) {
      int col = n0 + wn * 64 + nt * 16 + lr;
      float bv = b_out[col];
      #pragma unroll
      for (int mt = 0; mt < 8; ++mt) {
        int mbase = m0 + wm * 128 + mt * 16 + hi * 4;
        #pragma unroll
        for (int p = 0; p < 4; ++p) {
          int mp = mbase + p;
          int orow = (mp & 31) * 128 + (mp >> 5);
          out[(size_t)orow * VOC + col] = acc[mt][nt][p] + bv;
        }
      }
    }
    __syncthreads();   // all frag reads done before next tile's STAGE overwrites LDS
  }
}

__global__ __launch_bounds__(512, 1) void fused_kernel(
    const f16* __restrict__ Whh16, const float* __restrict__ XG2,
    const f16* __restrict__ h0f, f16* __restrict__ HS,
    const f16* __restrict__ Wout16, const float* __restrict__ b_out,
    float* __restrict__ out, unsigned* __restrict__ bar, unsigned* __restrict__ cnt,
    unsigned* __restrict__ gready) {
  __shared__ __align__(16) char smem[SM_SIZE];
  if (blockIdx.x < NLSTM)
    lstm_role(Whh16, XG2, h0f, HS, bar, gready, smem);
  worker_role(HS, Wout16, b_out, out, gready, cnt, smem);
}

extern "C" void kernel_launch(void* const* d_in, const int* in_sizes, int n_in,
                              void* d_out, int out_size, void* d_ws, size_t ws_size,
                              hipStream_t stream) {
  const float* z     = (const float*)d_in[0];
  const int*   x     = (const int*)d_in[1];
  const float* W_h   = (const float*)d_in[2];
  const float* b_h   = (const float*)d_in[3];
  const float* emb   = (const float*)d_in[4];
  const float* W_ih  = (const float*)d_in[5];
  const float* W_hh  = (const float*)d_in[6];
  const float* b_ih  = (const float*)d_in[7];
  const float* b_hh  = (const float*)d_in[8];
  const float* W_out = (const float*)d_in[9];
  const float* b_out = (const float*)d_in[10];
  float* out = (float*)d_out;

  char* ws = (char*)d_ws;
  size_t off = 0;
  auto carve = [&](size_t n) { char* p = ws + off; off += (n + 255) & ~(size_t)255; return p; };
  f16*   E16    = (f16*)carve((size_t)BT * DE * 2);     // 4 MB
  f16*   Wih16  = (f16*)carve((size_t)G4 * DE * 2);     // 4 MB
  f16*   Whh16  = (f16*)carve((size_t)G4 * HID * 2);    // 8 MB
  f16*   Wout16 = (f16*)carve((size_t)VOC * HID * 2);   // 64 MB
  float* XG2    = (float*)carve((size_t)BT * G4 * 4);   // 64 MB, [g][b][t]
  f16*   HS     = (f16*)carve((size_t)BT * HID * 2);    // 8 MB, t-major rows
  f16*   h0f    = (f16*)carve((size_t)Bb * HID * 2);
  float* bs     = (float*)carve((size_t)G4 * 4);
  unsigned* bar    = (unsigned*)carve(256);
  unsigned* cnt    = (unsigned*)carve(256);
  unsigned* gready = (unsigned*)carve(256);

  (void)hipMemsetAsync(bar, 0, 768, stream);   // bar + cnt + gready (contiguous)

  cvt_kernel<<<2048, 256, 0, stream>>>(W_ih,  Wih16,  G4 * DE / 4);
  cvt_kernel<<<2048, 256, 0, stream>>>(W_hh,  Whh16,  G4 * HID / 4);
  cvt_kernel<<<2048, 256, 0, stream>>>(W_out, Wout16, VOC * HID / 4);
  gather_kernel<<<BT * DE / 8 / 256, 256, 0, stream>>>(emb, x, E16);
  bsum_kernel<<<16, 256, 0, stream>>>(b_ih, b_hh, bs, G4);
  h0_kernel<<<128, 256, 0, stream>>>(z, W_h, b_h, h0f);

  dim3 g1(G4 / 128, BT / 128);     // 32 x 32
  gemmxg_kernel<<<g1, 256, 0, stream>>>(E16, Wih16, bs, XG2, BT, G4, DE);

  fused_kernel<<<256, 512, 0, stream>>>(Whh16, XG2, h0f, HS, Wout16, b_out, out,
                                        bar, cnt, gready);
}

// Round 16
// 907.462 us; speedup vs baseline: 1.6133x; 1.0283x over previous
//
#include <hip/hip_runtime.h>

typedef _Float16 f16;
typedef _Float16 f16x8 __attribute__((ext_vector_type(8)));
typedef _Float16 f16x4 __attribute__((ext_vector_type(4)));
typedef float    f32x4 __attribute__((ext_vector_type(4)));
typedef unsigned long long ull;

static constexpr int Bb  = 32;
static constexpr int Tt  = 128;
static constexpr int HID = 1024;
static constexpr int ZD  = 256;
static constexpr int DE  = 512;
static constexpr int VOC = 32000;
static constexpr int BT  = Bb * Tt;   // 4096
static constexpr int G4  = 4 * HID;   // 4096
static constexpr int NLSTM = 64;      // lstm-role blocks (16 hidden units each)
static constexpr int NTILES = (BT / 256) * (VOC / 256);  // 16 * 125 = 2000
// HS layout is T-MAJOR: row m' = t*32 + b. Writes are agent-scope; all reads are
// flag-gated after the writes, so normal cached loads are coherent.

// ---- async global->LDS, 16B per lane; LDS dest = wave-uniform base + lane*16 ----
__device__ __forceinline__ void gld_lds16(const void* g, void* l) {
  __builtin_amdgcn_global_load_lds((const __attribute__((address_space(1))) unsigned int*)g,
                                   (__attribute__((address_space(3))) unsigned int*)l,
                                   16, 0, 0);
}

// ---------------- f32 -> f16 convert (vectorized) ----------------
__global__ void cvt_kernel(const float* __restrict__ s, f16* __restrict__ d, int n4) {
  int i = blockIdx.x * blockDim.x + threadIdx.x;
  int st = gridDim.x * blockDim.x;
  for (; i < n4; i += st) {
    float4 v = ((const float4*)s)[i];
    f16x4 o = { (f16)v.x, (f16)v.y, (f16)v.z, (f16)v.w };
    ((f16x4*)d)[i] = o;
  }
}

// ---------------- embedding gather -> f16 ----------------
__global__ void gather_kernel(const float* __restrict__ emb, const int* __restrict__ x,
                              f16* __restrict__ E) {
  int g = blockIdx.x * 256 + threadIdx.x;   // BT*DE/8 threads
  int m = g >> 6, seg = (g & 63) * 8;
  int idx = x[m];
  const float* src = emb + (size_t)idx * DE + seg;
  float4 a = *(const float4*)src;
  float4 b = *(const float4*)(src + 4);
  f16x8 o = { (f16)a.x,(f16)a.y,(f16)a.z,(f16)a.w,(f16)b.x,(f16)b.y,(f16)b.z,(f16)b.w };
  *(f16x8*)(E + (size_t)m * DE + seg) = o;
}

// ---------------- bias sum ----------------
__global__ void bsum_kernel(const float* __restrict__ a, const float* __restrict__ b,
                            float* __restrict__ o, int n) {
  int i = blockIdx.x * blockDim.x + threadIdx.x;
  if (i < n) o[i] = a[i] + b[i];
}

// ---------------- h0 = tanh(z @ W_h^T + b_h), store f16 ----------------
__global__ __launch_bounds__(256) void h0_kernel(const float* __restrict__ z,
                                                 const float* __restrict__ W_h,
                                                 const float* __restrict__ b_h,
                                                 f16* __restrict__ h0f) {
  __shared__ float zs[32][260];
  __shared__ float wsl[8][260];
  const int jc = blockIdx.x, tid = threadIdx.x;
  #pragma unroll
  for (int it = 0; it < 8; ++it) {
    int idx = it * 256 + tid;
    float4 v = ((const float4*)z)[idx];
    int b = idx >> 6, k = (idx & 63) * 4;
    zs[b][k] = v.x; zs[b][k+1] = v.y; zs[b][k+2] = v.z; zs[b][k+3] = v.w;
  }
  #pragma unroll
  for (int it = 0; it < 2; ++it) {
    int idx = it * 256 + tid;
    float4 v = ((const float4*)(W_h + (size_t)jc * 8 * ZD))[idx];
    int r = idx >> 6, k = (idx & 63) * 4;
    wsl[r][k] = v.x; wsl[r][k+1] = v.y; wsl[r][k+2] = v.z; wsl[r][k+3] = v.w;
  }
  __syncthreads();
  const int b = tid >> 3, jj = tid & 7;
  const int j = jc * 8 + jj;
  float acc = b_h[j];
  for (int k = 0; k < ZD; ++k) acc += zs[b][k] * wsl[jj][k];
  h0f[(size_t)b * HID + j] = (f16)tanhf(acc);
}

// ---------------- GEMM 128x128 (proven): C = A @ B^T + bias, XG output layout ---
__global__ __launch_bounds__(256, 2) void gemmxg_kernel(
    const f16* __restrict__ A, const f16* __restrict__ B,
    const float* __restrict__ bias, float* __restrict__ C,
    int M, int N, int K) {
  __shared__ f16 As[128 * 64];
  __shared__ f16 Bs[128 * 64];
  const int n0 = blockIdx.x * 128, m0 = blockIdx.y * 128;
  const int tid = threadIdx.x, wid = tid >> 6, lane = tid & 63;
  const int wm = wid >> 1, wn = wid & 1;
  const int sr = lane >> 3, sk = (lane & 7) * 8;
  f32x4 acc[4][4] = {};
  for (int k0 = 0; k0 < K; k0 += 64) {
    __syncthreads();
    #pragma unroll
    for (int i = 0; i < 4; ++i) {
      int rr = (wid * 4 + i) * 8;
      gld_lds16(A + (size_t)(m0 + rr + sr) * K + k0 + sk, &As[rr * 64]);
      gld_lds16(B + (size_t)(n0 + rr + sr) * K + k0 + sk, &Bs[rr * 64]);
    }
    __syncthreads();
    #pragma unroll
    for (int ks = 0; ks < 2; ++ks) {
      f16x8 af[4], bf[4];
      #pragma unroll
      for (int mt = 0; mt < 4; ++mt)
        af[mt] = *(const f16x8*)&As[(wm * 64 + mt * 16 + (lane & 15)) * 64 + ks * 32 + (lane >> 4) * 8];
      #pragma unroll
      for (int nt = 0; nt < 4; ++nt)
        bf[nt] = *(const f16x8*)&Bs[(wn * 64 + nt * 16 + (lane & 15)) * 64 + ks * 32 + (lane >> 4) * 8];
      #pragma unroll
      for (int mt = 0; mt < 4; ++mt)
        #pragma unroll
        for (int nt = 0; nt < 4; ++nt)
          acc[mt][nt] = __builtin_amdgcn_mfma_f32_16x16x32_f16(af[mt], bf[nt], acc[mt][nt], 0, 0, 0);
    }
  }
  #pragma unroll
  for (int nt = 0; nt < 4; ++nt) {
    int col = n0 + wn * 64 + nt * 16 + (lane & 15);
    float bv = bias[col];
    #pragma unroll
    for (int mt = 0; mt < 4; ++mt) {
      int row = m0 + wm * 64 + mt * 16 + (lane >> 4) * 4;
      int b = row >> 7, t0 = row & 127;
      float4 v = { acc[mt][nt][0] + bv, acc[mt][nt][1] + bv,
                   acc[mt][nt][2] + bv, acc[mt][nt][3] + bv };
      *(float4*)&C[((size_t)col * 32 + b) * 128 + t0] = v;
    }
  }
}

// =================================================================================
// FUSED persistent kernel: 256 blocks x 512 threads, 1 block/CU (capacity-resident).
//   blocks 0..63 : LSTM recurrence role (t-major HS), then join worker pool.
//   blocks 64..255: GEMM workers from the start.
// lstm v6 step structure (this round): column-sliced staging (wave-private),
// per-wave producer gating via LDS flag mirror; only 2 barriers/step.
// =================================================================================
static constexpr int SM_HL   = 0;                       // f16 hl[32][1032] = 66048 B
static constexpr int SM_PART = 66048;                   // float part[8][64][33] = 67584 B
static constexpr int SM_FL   = 133632;                  // unsigned fl[64] mirror = 256 B
static constexpr int SM_IDX  = 133888;                  // unsigned sIdx
static constexpr int SM_SIZE = 133904;

__device__ void lstm_role(const f16* __restrict__ Whh16, const float* __restrict__ XG2,
                          const f16* __restrict__ h0f, f16* __restrict__ HS,
                          unsigned* __restrict__ bar, unsigned* __restrict__ gready,
                          char* smem) {
  const int bid = blockIdx.x, tid = threadIdx.x;
  const int lane = tid & 63, wid = tid >> 6;
  const int lr = lane & 15, hi = lane >> 4;
  const int j0 = bid * 16;
  f16 (*hl)[1032] = (f16 (*)[1032])(smem + SM_HL);
  float (*part)[64][33] = (float (*)[64][33])(smem + SM_PART);
  unsigned* fl = (unsigned*)(smem + SM_FL);

  if (tid < 64) fl[tid] = 0;

  f16x8 wfrag[4][4];
  #pragma unroll
  for (int rt = 0; rt < 4; ++rt) {
    int g = rt * HID + j0 + lr;
    #pragma unroll
    for (int kk = 0; kk < 4; ++kk)
      wfrag[rt][kk] = *(const f16x8*)(Whh16 + (size_t)g * HID + wid * 128 + kk * 32 + hi * 8);
  }

  const int ub = tid & 15, bb = tid >> 4;
  float creg = 0.f;
  __syncthreads();   // fl init visible

  for (int t = 0; t < Tt; ++t) {
    float xg[4];
    #pragma unroll
    for (int q = 0; q < 4; ++q)
      xg[q] = XG2[((size_t)(q * HID + j0 + ub) * 32 + bb) * 128 + t];

    // ---- per-wave readiness: wave 0 polls bar + mirrors to LDS; waves 1..7
    //      spin on the LDS mirror for THEIR 8 producers only ----
    if (t > 0) {
      if (wid == 0) {
        for (;;) {
          unsigned f = __hip_atomic_load(&bar[lane], __ATOMIC_RELAXED, __HIP_MEMORY_SCOPE_AGENT);
          __hip_atomic_store(&fl[lane], f, __ATOMIC_RELAXED, __HIP_MEMORY_SCOPE_WORKGROUP);
          if (__all(f >= (unsigned)t)) break;
        }
        if (bid == 0 && lane == 0)
          __hip_atomic_store(gready, (unsigned)t, __ATOMIC_RELAXED, __HIP_MEMORY_SCOPE_AGENT);
      } else {
        const int p = wid * 8 + (lane & 7);
        for (;;) {
          unsigned f = __hip_atomic_load(&fl[p], __ATOMIC_RELAXED, __HIP_MEMORY_SCOPE_WORKGROUP);
          if (__all(f >= (unsigned)t)) break;
        }
      }
    }

    // ---- stage own k-slice: wave wid loads ALL 32 batch rows x units
    //      [wid*128, wid*128+128) -- wave-private, no barrier needed ----
    {
      const int uo = wid * 128 + (lane & 31) * 4;   // ull = 4 units
      #pragma unroll
      for (int ps = 0; ps < 16; ++ps) {
        int row = ps * 2 + (lane >> 5);
        const f16* hb = (t == 0) ? (h0f + (size_t)row * HID)
                                 : (HS + (size_t)((t - 1) * 32 + row) * HID);
        ull v = *(const ull*)(hb + uo);
        *(ull*)&hl[row][uo] = v;
      }
    }

    // ---- gate MFMA: C[64 gate rows][32 batches], this wave's k-eighth ----
    {
      f32x4 acc[4][2] = {};
      #pragma unroll
      for (int kk = 0; kk < 4; ++kk) {
        int ko = wid * 128 + kk * 32 + hi * 8;
        f16x8 bf0 = *(const f16x8*)&hl[lr][ko];
        f16x8 bf1 = *(const f16x8*)&hl[16 + lr][ko];
        #pragma unroll
        for (int rt = 0; rt < 4; ++rt) {
          acc[rt][0] = __builtin_amdgcn_mfma_f32_16x16x32_f16(wfrag[rt][kk], bf0, acc[rt][0], 0, 0, 0);
          acc[rt][1] = __builtin_amdgcn_mfma_f32_16x16x32_f16(wfrag[rt][kk], bf1, acc[rt][1], 0, 0, 0);
        }
      }
      #pragma unroll
      for (int rt = 0; rt < 4; ++rt)
        #pragma unroll
        for (int bt = 0; bt < 2; ++bt)
          #pragma unroll
          for (int p = 0; p < 4; ++p)
            part[wid][rt * 16 + hi * 4 + p][bt * 16 + lr] = acc[rt][bt][p];
    }
    __syncthreads();   // S1: part complete (and all waves past their hl reads)

    // ---- LSTM update: thread (ub, bb); h store agent-coherent 2B, t-major ----
    {
      float g4[4];
      #pragma unroll
      for (int q = 0; q < 4; ++q) {
        int i = q * 16 + ub;
        float s = xg[q];
        #pragma unroll
        for (int w = 0; w < 8; ++w) s += part[w][i][bb];
        g4[q] = s;
      }
      float ig = 1.f / (1.f + __expf(-g4[0]));
      float fg = 1.f / (1.f + __expf(-g4[1]));
      float gg = tanhf(g4[2]);
      float og = 1.f / (1.f + __expf(-g4[3]));
      creg = fg * creg + ig * gg;
      float h = og * tanhf(creg);
      union { f16 h; unsigned short u; } cv;
      cv.h = (f16)h;
      __hip_atomic_store((unsigned short*)&HS[(size_t)(t * 32 + bb) * HID + j0 + ub],
                         cv.u, __ATOMIC_RELAXED, __HIP_MEMORY_SCOPE_AGENT);
    }

    // ---- drain + flag (every t; workers need t=127 too) ----
    asm volatile("s_waitcnt vmcnt(0)" ::: "memory");
    __syncthreads();   // S2: all h stores at IF
    if (tid == 0)
      __hip_atomic_store(&bar[bid], (unsigned)(t + 1),
                         __ATOMIC_RELAXED, __HIP_MEMORY_SCOPE_AGENT);
  }

  // block 0: final aggregation (flags reach 128 only after all finish t=127)
  if (bid == 0) {
    if (wid == 0) {
      for (;;) {
        unsigned f = __hip_atomic_load(&bar[lane], __ATOMIC_RELAXED, __HIP_MEMORY_SCOPE_AGENT);
        if (__all(f >= (unsigned)Tt)) break;
      }
      if (lane == 0)
        __hip_atomic_store(gready, (unsigned)Tt, __ATOMIC_RELAXED, __HIP_MEMORY_SCOPE_AGENT);
    }
    __syncthreads();
  }
}

__device__ void worker_role(const f16* __restrict__ HS, const f16* __restrict__ Wout16,
                            const float* __restrict__ b_out, float* __restrict__ out,
                            unsigned* __restrict__ gready, unsigned* __restrict__ cnt,
                            char* smem) {
  const int tid = threadIdx.x, wid = tid >> 6, lane = tid & 63;
  const int wm = wid >> 2, wn = wid & 3;
  const int lr = lane & 15, hi = lane >> 4;
  const int srow = lane >> 2;
  const int scol = ((lane & 3) ^ ((lane >> 3) & 3)) * 8;   // pre-swizzled source col
  const int sx   = (hi ^ ((lr >> 1) & 3)) * 8;             // swizzled read slot
  f16* As = (f16*)(smem);            // [4][8192] halves = 65536 B
  f16* Bs = (f16*)(smem + 65536);    // [4][8192]
  unsigned* sIdx = (unsigned*)(smem + SM_IDX);
  const int cb0 = wid * 2, cb1 = wid * 2 + 1;

  for (;;) {
    if (tid == 0) *sIdx = atomicAdd(cnt, 1u);
    __syncthreads();
    unsigned idx = *sIdx;
    if (idx >= (unsigned)NTILES) break;
    int mg = idx / 125, ng = idx - mg * 125;
    // readiness: single aggregated word, s_sleep backoff
    if (wid == 0) {
      const unsigned tgt = (unsigned)(8 * mg + 8);
      for (;;) {
        unsigned g = __hip_atomic_load(gready, __ATOMIC_RELAXED, __HIP_MEMORY_SCOPE_AGENT);
        if (g >= tgt) break;
        __builtin_amdgcn_s_sleep(64);
      }
    }
    __syncthreads();

    const int m0 = mg * 256, n0 = ng * 256;
    f32x4 acc[8][4] = {};

    auto STAGE = [&](int kt) {
      const int k0 = kt << 5, buf = kt & 3;
      gld_lds16(HS     + (size_t)(m0 + cb0 * 16 + srow) * HID + k0 + scol, As + buf * 8192 + cb0 * 512);
      gld_lds16(Wout16 + (size_t)(n0 + cb0 * 16 + srow) * HID + k0 + scol, Bs + buf * 8192 + cb0 * 512);
      gld_lds16(HS     + (size_t)(m0 + cb1 * 16 + srow) * HID + k0 + scol, As + buf * 8192 + cb1 * 512);
      gld_lds16(Wout16 + (size_t)(n0 + cb1 * 16 + srow) * HID + k0 + scol, Bs + buf * 8192 + cb1 * 512);
    };

    STAGE(0); STAGE(1); STAGE(2);
    for (int kt = 0; kt < 32; ++kt) {
      if (kt < 30)       asm volatile("s_waitcnt vmcnt(8)" ::: "memory");
      else if (kt == 30) asm volatile("s_waitcnt vmcnt(4)" ::: "memory");
      else               asm volatile("s_waitcnt vmcnt(0)" ::: "memory");
      __builtin_amdgcn_s_barrier();
      if (kt + 3 < 32) STAGE(kt + 3);
      const f16* as = As + (kt & 3) * 8192;
      const f16* bs = Bs + (kt & 3) * 8192;
      f16x8 af[8], bf[4];
      #pragma unroll
      for (int mt = 0; mt < 8; ++mt)
        af[mt] = *(const f16x8*)&as[(wm * 128 + mt * 16 + lr) * 32 + sx];
      #pragma unroll
      for (int nt = 0; nt < 4; ++nt)
        bf[nt] = *(const f16x8*)&bs[(wn * 64 + nt * 16 + lr) * 32 + sx];
      __builtin_amdgcn_s_setprio(1);
      #pragma unroll
      for (int mt = 0; mt < 8; ++mt)
        #pragma unroll
        for (int nt = 0; nt < 4; ++nt)
          acc[mt][nt] = __builtin_amdgcn_mfma_f32_16x16x32_f16(af[mt], bf[nt], acc[mt][nt], 0, 0, 0);
      __builtin_amdgcn_s_setprio(0);
    }

    // epilogue: un-permute rows (m' = t*32+b -> out row b*128+t), add bias
    #pragma unroll
    for (int nt = 0; nt < 4; ++nt) {
      int col = n0 + wn * 64 + nt * 16 + lr;
      float bv = b_out[col];
      #pragma unroll
      for (int mt = 0; mt < 8; ++mt) {
        int mbase = m0 + wm * 128 + mt * 16 + hi * 4;
        #pragma unroll
        for (int p = 0; p < 4; ++p) {
          int mp = mbase + p;
          int orow = (mp & 31) * 128 + (mp >> 5);
          out[(size_t)orow * VOC + col] = acc[mt][nt][p] + bv;
        }
      }
    }
    __syncthreads();   // all frag reads done before next tile's STAGE overwrites LDS
  }
}

__global__ __launch_bounds__(512, 1) void fused_kernel(
    const f16* __restrict__ Whh16, const float* __restrict__ XG2,
    const f16* __restrict__ h0f, f16* __restrict__ HS,
    const f16* __restrict__ Wout16, const float* __restrict__ b_out,
    float* __restrict__ out, unsigned* __restrict__ bar, unsigned* __restrict__ cnt,
    unsigned* __restrict__ gready) {
  __shared__ __align__(16) char smem[SM_SIZE];
  if (blockIdx.x < NLSTM)
    lstm_role(Whh16, XG2, h0f, HS, bar, gready, smem);
  worker_role(HS, Wout16, b_out, out, gready, cnt, smem);
}

extern "C" void kernel_launch(void* const* d_in, const int* in_sizes, int n_in,
                              void* d_out, int out_size, void* d_ws, size_t ws_size,
                              hipStream_t stream) {
  const float* z     = (const float*)d_in[0];
  const int*   x     = (const int*)d_in[1];
  const float* W_h   = (const float*)d_in[2];
  const float* b_h   = (const float*)d_in[3];
  const float* emb   = (const float*)d_in[4];
  const float* W_ih  = (const float*)d_in[5];
  const float* W_hh  = (const float*)d_in[6];
  const float* b_ih  = (const float*)d_in[7];
  const float* b_hh  = (const float*)d_in[8];
  const float* W_out = (const float*)d_in[9];
  const float* b_out = (const float*)d_in[10];
  float* out = (float*)d_out;

  char* ws = (char*)d_ws;
  size_t off = 0;
  auto carve = [&](size_t n) { char* p = ws + off; off += (n + 255) & ~(size_t)255; return p; };
  f16*   E16    = (f16*)carve((size_t)BT * DE * 2);     // 4 MB
  f16*   Wih16  = (f16*)carve((size_t)G4 * DE * 2);     // 4 MB
  f16*   Whh16  = (f16*)carve((size_t)G4 * HID * 2);    // 8 MB
  f16*   Wout16 = (f16*)carve((size_t)VOC * HID * 2);   // 64 MB
  float* XG2    = (float*)carve((size_t)BT * G4 * 4);   // 64 MB, [g][b][t]
  f16*   HS     = (f16*)carve((size_t)BT * HID * 2);    // 8 MB, t-major rows
  f16*   h0f    = (f16*)carve((size_t)Bb * HID * 2);
  float* bs     = (float*)carve((size_t)G4 * 4);
  unsigned* bar    = (unsigned*)carve(256);
  unsigned* cnt    = (unsigned*)carve(256);
  unsigned* gready = (unsigned*)carve(256);

  (void)hipMemsetAsync(bar, 0, 768, stream);   // bar + cnt + gready (contiguous)

  cvt_kernel<<<2048, 256, 0, stream>>>(W_ih,  Wih16,  G4 * DE / 4);
  cvt_kernel<<<2048, 256, 0, stream>>>(W_hh,  Whh16,  G4 * HID / 4);
  cvt_kernel<<<2048, 256, 0, stream>>>(W_out, Wout16, VOC * HID / 4);
  gather_kernel<<<BT * DE / 8 / 256, 256, 0, stream>>>(emb, x, E16);
  bsum_kernel<<<16, 256, 0, stream>>>(b_ih, b_hh, bs, G4);
  h0_kernel<<<128, 256, 0, stream>>>(z, W_h, b_h, h0f);

  dim3 g1(G4 / 128, BT / 128);     // 32 x 32
  gemmxg_kernel<<<g1, 256, 0, stream>>>(E16, Wih16, bs, XG2, BT, G4, DE);

  fused_kernel<<<256, 512, 0, stream>>>(Whh16, XG2, h0f, HS, Wout16, b_out, out,
                                        bar, cnt, gready);
}

// Round 17
// 848.057 us; speedup vs baseline: 1.7263x; 1.0700x over previous
//
#include <hip/hip_runtime.h>

typedef _Float16 f16;
typedef _Float16 f16x8 __attribute__((ext_vector_type(8)));
typedef _Float16 f16x4 __attribute__((ext_vector_type(4)));
typedef float    f32x4 __attribute__((ext_vector_type(4)));
typedef unsigned long long ull;

static constexpr int Bb  = 32;
static constexpr int Tt  = 128;
static constexpr int HID = 1024;
static constexpr int ZD  = 256;
static constexpr int DE  = 512;
static constexpr int VOC = 32000;
static constexpr int BT  = Bb * Tt;   // 4096
static constexpr int G4  = 4 * HID;   // 4096
static constexpr int NLSTM = 64;      // lstm-role blocks (16 hidden units each)
static constexpr int NTILES = (BT / 256) * (VOC / 256);  // 16 * 125 = 2000
// HS layout is T-MAJOR: row m' = t*32 + b. Writes are agent-scope; all reads are
// flag-gated after the writes, so normal cached loads are coherent.
// out stores are NON-TEMPORAL: out is write-once/never-read -> keep it out of
// L2/L3 so Wout16/XG2 stay cache-resident (round-17 change).

// ---- async global->LDS, 16B per lane; LDS dest = wave-uniform base + lane*16 ----
__device__ __forceinline__ void gld_lds16(const void* g, void* l) {
  __builtin_amdgcn_global_load_lds((const __attribute__((address_space(1))) unsigned int*)g,
                                   (__attribute__((address_space(3))) unsigned int*)l,
                                   16, 0, 0);
}

// ---------------- f32 -> f16 convert (vectorized) ----------------
__global__ void cvt_kernel(const float* __restrict__ s, f16* __restrict__ d, int n4) {
  int i = blockIdx.x * blockDim.x + threadIdx.x;
  int st = gridDim.x * blockDim.x;
  for (; i < n4; i += st) {
    float4 v = ((const float4*)s)[i];
    f16x4 o = { (f16)v.x, (f16)v.y, (f16)v.z, (f16)v.w };
    ((f16x4*)d)[i] = o;
  }
}

// ---------------- embedding gather -> f16 ----------------
__global__ void gather_kernel(const float* __restrict__ emb, const int* __restrict__ x,
                              f16* __restrict__ E) {
  int g = blockIdx.x * 256 + threadIdx.x;   // BT*DE/8 threads
  int m = g >> 6, seg = (g & 63) * 8;
  int idx = x[m];
  const float* src = emb + (size_t)idx * DE + seg;
  float4 a = *(const float4*)src;
  float4 b = *(const float4*)(src + 4);
  f16x8 o = { (f16)a.x,(f16)a.y,(f16)a.z,(f16)a.w,(f16)b.x,(f16)b.y,(f16)b.z,(f16)b.w };
  *(f16x8*)(E + (size_t)m * DE + seg) = o;
}

// ---------------- bias sum ----------------
__global__ void bsum_kernel(const float* __restrict__ a, const float* __restrict__ b,
                            float* __restrict__ o, int n) {
  int i = blockIdx.x * blockDim.x + threadIdx.x;
  if (i < n) o[i] = a[i] + b[i];
}

// ---------------- h0 = tanh(z @ W_h^T + b_h), store f16 ----------------
__global__ __launch_bounds__(256) void h0_kernel(const float* __restrict__ z,
                                                 const float* __restrict__ W_h,
                                                 const float* __restrict__ b_h,
                                                 f16* __restrict__ h0f) {
  __shared__ float zs[32][260];
  __shared__ float wsl[8][260];
  const int jc = blockIdx.x, tid = threadIdx.x;
  #pragma unroll
  for (int it = 0; it < 8; ++it) {
    int idx = it * 256 + tid;
    float4 v = ((const float4*)z)[idx];
    int b = idx >> 6, k = (idx & 63) * 4;
    zs[b][k] = v.x; zs[b][k+1] = v.y; zs[b][k+2] = v.z; zs[b][k+3] = v.w;
  }
  #pragma unroll
  for (int it = 0; it < 2; ++it) {
    int idx = it * 256 + tid;
    float4 v = ((const float4*)(W_h + (size_t)jc * 8 * ZD))[idx];
    int r = idx >> 6, k = (idx & 63) * 4;
    wsl[r][k] = v.x; wsl[r][k+1] = v.y; wsl[r][k+2] = v.z; wsl[r][k+3] = v.w;
  }
  __syncthreads();
  const int b = tid >> 3, jj = tid & 7;
  const int j = jc * 8 + jj;
  float acc = b_h[j];
  for (int k = 0; k < ZD; ++k) acc += zs[b][k] * wsl[jj][k];
  h0f[(size_t)b * HID + j] = (f16)tanhf(acc);
}

// ---------------- GEMM 128x128 (proven): C = A @ B^T + bias, XG output layout ---
__global__ __launch_bounds__(256, 2) void gemmxg_kernel(
    const f16* __restrict__ A, const f16* __restrict__ B,
    const float* __restrict__ bias, float* __restrict__ C,
    int M, int N, int K) {
  __shared__ f16 As[128 * 64];
  __shared__ f16 Bs[128 * 64];
  const int n0 = blockIdx.x * 128, m0 = blockIdx.y * 128;
  const int tid = threadIdx.x, wid = tid >> 6, lane = tid & 63;
  const int wm = wid >> 1, wn = wid & 1;
  const int sr = lane >> 3, sk = (lane & 7) * 8;
  f32x4 acc[4][4] = {};
  for (int k0 = 0; k0 < K; k0 += 64) {
    __syncthreads();
    #pragma unroll
    for (int i = 0; i < 4; ++i) {
      int rr = (wid * 4 + i) * 8;
      gld_lds16(A + (size_t)(m0 + rr + sr) * K + k0 + sk, &As[rr * 64]);
      gld_lds16(B + (size_t)(n0 + rr + sr) * K + k0 + sk, &Bs[rr * 64]);
    }
    __syncthreads();
    #pragma unroll
    for (int ks = 0; ks < 2; ++ks) {
      f16x8 af[4], bf[4];
      #pragma unroll
      for (int mt = 0; mt < 4; ++mt)
        af[mt] = *(const f16x8*)&As[(wm * 64 + mt * 16 + (lane & 15)) * 64 + ks * 32 + (lane >> 4) * 8];
      #pragma unroll
      for (int nt = 0; nt < 4; ++nt)
        bf[nt] = *(const f16x8*)&Bs[(wn * 64 + nt * 16 + (lane & 15)) * 64 + ks * 32 + (lane >> 4) * 8];
      #pragma unroll
      for (int mt = 0; mt < 4; ++mt)
        #pragma unroll
        for (int nt = 0; nt < 4; ++nt)
          acc[mt][nt] = __builtin_amdgcn_mfma_f32_16x16x32_f16(af[mt], bf[nt], acc[mt][nt], 0, 0, 0);
    }
  }
  #pragma unroll
  for (int nt = 0; nt < 4; ++nt) {
    int col = n0 + wn * 64 + nt * 16 + (lane & 15);
    float bv = bias[col];
    #pragma unroll
    for (int mt = 0; mt < 4; ++mt) {
      int row = m0 + wm * 64 + mt * 16 + (lane >> 4) * 4;
      int b = row >> 7, t0 = row & 127;
      float4 v = { acc[mt][nt][0] + bv, acc[mt][nt][1] + bv,
                   acc[mt][nt][2] + bv, acc[mt][nt][3] + bv };
      *(float4*)&C[((size_t)col * 32 + b) * 128 + t0] = v;
    }
  }
}

// =================================================================================
// FUSED persistent kernel: 256 blocks x 512 threads, 1 block/CU (capacity-resident).
//   blocks 0..63 : LSTM recurrence role (t-major HS), then join worker pool.
//   blocks 64..255: GEMM workers from the start.
// lstm: column-sliced staging (wave-private), per-wave producer gating via LDS
// flag mirror, 2 barriers/step. Workers poll one aggregated word (gready).
// Worker epilogue uses NON-TEMPORAL out stores (L3 stays Wout/XG-resident).
// =================================================================================
static constexpr int SM_HL   = 0;                       // f16 hl[32][1032] = 66048 B
static constexpr int SM_PART = 66048;                   // float part[8][64][33] = 67584 B
static constexpr int SM_FL   = 133632;                  // unsigned fl[64] mirror = 256 B
static constexpr int SM_IDX  = 133888;                  // unsigned sIdx
static constexpr int SM_SIZE = 133904;

__device__ void lstm_role(const f16* __restrict__ Whh16, const float* __restrict__ XG2,
                          const f16* __restrict__ h0f, f16* __restrict__ HS,
                          unsigned* __restrict__ bar, unsigned* __restrict__ gready,
                          char* smem) {
  const int bid = blockIdx.x, tid = threadIdx.x;
  const int lane = tid & 63, wid = tid >> 6;
  const int lr = lane & 15, hi = lane >> 4;
  const int j0 = bid * 16;
  f16 (*hl)[1032] = (f16 (*)[1032])(smem + SM_HL);
  float (*part)[64][33] = (float (*)[64][33])(smem + SM_PART);
  unsigned* fl = (unsigned*)(smem + SM_FL);

  if (tid < 64) fl[tid] = 0;

  f16x8 wfrag[4][4];
  #pragma unroll
  for (int rt = 0; rt < 4; ++rt) {
    int g = rt * HID + j0 + lr;
    #pragma unroll
    for (int kk = 0; kk < 4; ++kk)
      wfrag[rt][kk] = *(const f16x8*)(Whh16 + (size_t)g * HID + wid * 128 + kk * 32 + hi * 8);
  }

  const int ub = tid & 15, bb = tid >> 4;
  float creg = 0.f;
  __syncthreads();   // fl init visible

  for (int t = 0; t < Tt; ++t) {
    float xg[4];
    #pragma unroll
    for (int q = 0; q < 4; ++q)
      xg[q] = XG2[((size_t)(q * HID + j0 + ub) * 32 + bb) * 128 + t];

    // ---- per-wave readiness: wave 0 polls bar + mirrors to LDS; waves 1..7
    //      spin on the LDS mirror for THEIR 8 producers only ----
    if (t > 0) {
      if (wid == 0) {
        for (;;) {
          unsigned f = __hip_atomic_load(&bar[lane], __ATOMIC_RELAXED, __HIP_MEMORY_SCOPE_AGENT);
          __hip_atomic_store(&fl[lane], f, __ATOMIC_RELAXED, __HIP_MEMORY_SCOPE_WORKGROUP);
          if (__all(f >= (unsigned)t)) break;
        }
        if (bid == 0 && lane == 0)
          __hip_atomic_store(gready, (unsigned)t, __ATOMIC_RELAXED, __HIP_MEMORY_SCOPE_AGENT);
      } else {
        const int p = wid * 8 + (lane & 7);
        for (;;) {
          unsigned f = __hip_atomic_load(&fl[p], __ATOMIC_RELAXED, __HIP_MEMORY_SCOPE_WORKGROUP);
          if (__all(f >= (unsigned)t)) break;
        }
      }
    }

    // ---- stage own k-slice: wave wid loads ALL 32 batch rows x units
    //      [wid*128, wid*128+128) -- wave-private, no barrier needed ----
    {
      const int uo = wid * 128 + (lane & 31) * 4;   // ull = 4 units
      #pragma unroll
      for (int ps = 0; ps < 16; ++ps) {
        int row = ps * 2 + (lane >> 5);
        const f16* hb = (t == 0) ? (h0f + (size_t)row * HID)
                                 : (HS + (size_t)((t - 1) * 32 + row) * HID);
        ull v = *(const ull*)(hb + uo);
        *(ull*)&hl[row][uo] = v;
      }
    }

    // ---- gate MFMA: C[64 gate rows][32 batches], this wave's k-eighth ----
    {
      f32x4 acc[4][2] = {};
      #pragma unroll
      for (int kk = 0; kk < 4; ++kk) {
        int ko = wid * 128 + kk * 32 + hi * 8;
        f16x8 bf0 = *(const f16x8*)&hl[lr][ko];
        f16x8 bf1 = *(const f16x8*)&hl[16 + lr][ko];
        #pragma unroll
        for (int rt = 0; rt < 4; ++rt) {
          acc[rt][0] = __builtin_amdgcn_mfma_f32_16x16x32_f16(wfrag[rt][kk], bf0, acc[rt][0], 0, 0, 0);
          acc[rt][1] = __builtin_amdgcn_mfma_f32_16x16x32_f16(wfrag[rt][kk], bf1, acc[rt][1], 0, 0, 0);
        }
      }
      #pragma unroll
      for (int rt = 0; rt < 4; ++rt)
        #pragma unroll
        for (int bt = 0; bt < 2; ++bt)
          #pragma unroll
          for (int p = 0; p < 4; ++p)
            part[wid][rt * 16 + hi * 4 + p][bt * 16 + lr] = acc[rt][bt][p];
    }
    __syncthreads();   // S1: part complete (and all waves past their hl reads)

    // ---- LSTM update: thread (ub, bb); h store agent-coherent 2B, t-major ----
    {
      float g4[4];
      #pragma unroll
      for (int q = 0; q < 4; ++q) {
        int i = q * 16 + ub;
        float s = xg[q];
        #pragma unroll
        for (int w = 0; w < 8; ++w) s += part[w][i][bb];
        g4[q] = s;
      }
      float ig = 1.f / (1.f + __expf(-g4[0]));
      float fg = 1.f / (1.f + __expf(-g4[1]));
      float gg = tanhf(g4[2]);
      float og = 1.f / (1.f + __expf(-g4[3]));
      creg = fg * creg + ig * gg;
      float h = og * tanhf(creg);
      union { f16 h; unsigned short u; } cv;
      cv.h = (f16)h;
      __hip_atomic_store((unsigned short*)&HS[(size_t)(t * 32 + bb) * HID + j0 + ub],
                         cv.u, __ATOMIC_RELAXED, __HIP_MEMORY_SCOPE_AGENT);
    }

    // ---- drain + flag (every t; workers need t=127 too) ----
    asm volatile("s_waitcnt vmcnt(0)" ::: "memory");
    __syncthreads();   // S2: all h stores at IF
    if (tid == 0)
      __hip_atomic_store(&bar[bid], (unsigned)(t + 1),
                         __ATOMIC_RELAXED, __HIP_MEMORY_SCOPE_AGENT);
  }

  // block 0: final aggregation (flags reach 128 only after all finish t=127)
  if (bid == 0) {
    if (wid == 0) {
      for (;;) {
        unsigned f = __hip_atomic_load(&bar[lane], __ATOMIC_RELAXED, __HIP_MEMORY_SCOPE_AGENT);
        if (__all(f >= (unsigned)Tt)) break;
      }
      if (lane == 0)
        __hip_atomic_store(gready, (unsigned)Tt, __ATOMIC_RELAXED, __HIP_MEMORY_SCOPE_AGENT);
    }
    __syncthreads();
  }
}

__device__ void worker_role(const f16* __restrict__ HS, const f16* __restrict__ Wout16,
                            const float* __restrict__ b_out, float* __restrict__ out,
                            unsigned* __restrict__ gready, unsigned* __restrict__ cnt,
                            char* smem) {
  const int tid = threadIdx.x, wid = tid >> 6, lane = tid & 63;
  const int wm = wid >> 2, wn = wid & 3;
  const int lr = lane & 15, hi = lane >> 4;
  const int srow = lane >> 2;
  const int scol = ((lane & 3) ^ ((lane >> 3) & 3)) * 8;   // pre-swizzled source col
  const int sx   = (hi ^ ((lr >> 1) & 3)) * 8;             // swizzled read slot
  f16* As = (f16*)(smem);            // [4][8192] halves = 65536 B
  f16* Bs = (f16*)(smem + 65536);    // [4][8192]
  unsigned* sIdx = (unsigned*)(smem + SM_IDX);
  const int cb0 = wid * 2, cb1 = wid * 2 + 1;

  for (;;) {
    if (tid == 0) *sIdx = atomicAdd(cnt, 1u);
    __syncthreads();
    unsigned idx = *sIdx;
    if (idx >= (unsigned)NTILES) break;
    int mg = idx / 125, ng = idx - mg * 125;
    // readiness: single aggregated word, s_sleep backoff
    if (wid == 0) {
      const unsigned tgt = (unsigned)(8 * mg + 8);
      for (;;) {
        unsigned g = __hip_atomic_load(gready, __ATOMIC_RELAXED, __HIP_MEMORY_SCOPE_AGENT);
        if (g >= tgt) break;
        __builtin_amdgcn_s_sleep(64);
      }
    }
    __syncthreads();

    const int m0 = mg * 256, n0 = ng * 256;
    f32x4 acc[8][4] = {};

    auto STAGE = [&](int kt) {
      const int k0 = kt << 5, buf = kt & 3;
      gld_lds16(HS     + (size_t)(m0 + cb0 * 16 + srow) * HID + k0 + scol, As + buf * 8192 + cb0 * 512);
      gld_lds16(Wout16 + (size_t)(n0 + cb0 * 16 + srow) * HID + k0 + scol, Bs + buf * 8192 + cb0 * 512);
      gld_lds16(HS     + (size_t)(m0 + cb1 * 16 + srow) * HID + k0 + scol, As + buf * 8192 + cb1 * 512);
      gld_lds16(Wout16 + (size_t)(n0 + cb1 * 16 + srow) * HID + k0 + scol, Bs + buf * 8192 + cb1 * 512);
    };

    STAGE(0); STAGE(1); STAGE(2);
    for (int kt = 0; kt < 32; ++kt) {
      if (kt < 30)       asm volatile("s_waitcnt vmcnt(8)" ::: "memory");
      else if (kt == 30) asm volatile("s_waitcnt vmcnt(4)" ::: "memory");
      else               asm volatile("s_waitcnt vmcnt(0)" ::: "memory");
      __builtin_amdgcn_s_barrier();
      if (kt + 3 < 32) STAGE(kt + 3);
      const f16* as = As + (kt & 3) * 8192;
      const f16* bs = Bs + (kt & 3) * 8192;
      f16x8 af[8], bf[4];
      #pragma unroll
      for (int mt = 0; mt < 8; ++mt)
        af[mt] = *(const f16x8*)&as[(wm * 128 + mt * 16 + lr) * 32 + sx];
      #pragma unroll
      for (int nt = 0; nt < 4; ++nt)
        bf[nt] = *(const f16x8*)&bs[(wn * 64 + nt * 16 + lr) * 32 + sx];
      __builtin_amdgcn_s_setprio(1);
      #pragma unroll
      for (int mt = 0; mt < 8; ++mt)
        #pragma unroll
        for (int nt = 0; nt < 4; ++nt)
          acc[mt][nt] = __builtin_amdgcn_mfma_f32_16x16x32_f16(af[mt], bf[nt], acc[mt][nt], 0, 0, 0);
      __builtin_amdgcn_s_setprio(0);
    }

    // epilogue: un-permute rows (m' = t*32+b -> out row b*128+t), add bias,
    // NON-TEMPORAL stores (out is write-once; keep it out of L2/L3)
    #pragma unroll
    for (int nt = 0; nt < 4; ++nt) {
      int col = n0 + wn * 64 + nt * 16 + lr;
      float bv = b_out[col];
      #pragma unroll
      for (int mt = 0; mt < 8; ++mt) {
        int mbase = m0 + wm * 128 + mt * 16 + hi * 4;
        #pragma unroll
        for (int p = 0; p < 4; ++p) {
          int mp = mbase + p;
          int orow = (mp & 31) * 128 + (mp >> 5);
          __builtin_nontemporal_store(acc[mt][nt][p] + bv,
                                      &out[(size_t)orow * VOC + col]);
        }
      }
    }
    __syncthreads();   // all frag reads done before next tile's STAGE overwrites LDS
  }
}

__global__ __launch_bounds__(512, 1) void fused_kernel(
    const f16* __restrict__ Whh16, const float* __restrict__ XG2,
    const f16* __restrict__ h0f, f16* __restrict__ HS,
    const f16* __restrict__ Wout16, const float* __restrict__ b_out,
    float* __restrict__ out, unsigned* __restrict__ bar, unsigned* __restrict__ cnt,
    unsigned* __restrict__ gready) {
  __shared__ __align__(16) char smem[SM_SIZE];
  if (blockIdx.x < NLSTM)
    lstm_role(Whh16, XG2, h0f, HS, bar, gready, smem);
  worker_role(HS, Wout16, b_out, out, gready, cnt, smem);
}

extern "C" void kernel_launch(void* const* d_in, const int* in_sizes, int n_in,
                              void* d_out, int out_size, void* d_ws, size_t ws_size,
                              hipStream_t stream) {
  const float* z     = (const float*)d_in[0];
  const int*   x     = (const int*)d_in[1];
  const float* W_h   = (const float*)d_in[2];
  const float* b_h   = (const float*)d_in[3];
  const float* emb   = (const float*)d_in[4];
  const float* W_ih  = (const float*)d_in[5];
  const float* W_hh  = (const float*)d_in[6];
  const float* b_ih  = (const float*)d_in[7];
  const float* b_hh  = (const float*)d_in[8];
  const float* W_out = (const float*)d_in[9];
  const float* b_out = (const float*)d_in[10];
  float* out = (float*)d_out;

  char* ws = (char*)d_ws;
  size_t off = 0;
  auto carve = [&](size_t n) { char* p = ws + off; off += (n + 255) & ~(size_t)255; return p; };
  f16*   E16    = (f16*)carve((size_t)BT * DE * 2);     // 4 MB
  f16*   Wih16  = (f16*)carve((size_t)G4 * DE * 2);     // 4 MB
  f16*   Whh16  = (f16*)carve((size_t)G4 * HID * 2);    // 8 MB
  f16*   Wout16 = (f16*)carve((size_t)VOC * HID * 2);   // 64 MB
  float* XG2    = (float*)carve((size_t)BT * G4 * 4);   // 64 MB, [g][b][t]
  f16*   HS     = (f16*)carve((size_t)BT * HID * 2);    // 8 MB, t-major rows
  f16*   h0f    = (f16*)carve((size_t)Bb * HID * 2);
  float* bs     = (float*)carve((size_t)G4 * 4);
  unsigned* bar    = (unsigned*)carve(256);
  unsigned* cnt    = (unsigned*)carve(256);
  unsigned* gready = (unsigned*)carve(256);

  (void)hipMemsetAsync(bar, 0, 768, stream);   // bar + cnt + gready (contiguous)

  cvt_kernel<<<2048, 256, 0, stream>>>(W_ih,  Wih16,  G4 * DE / 4);
  cvt_kernel<<<2048, 256, 0, stream>>>(W_hh,  Whh16,  G4 * HID / 4);
  cvt_kernel<<<2048, 256, 0, stream>>>(W_out, Wout16, VOC * HID / 4);
  gather_kernel<<<BT * DE / 8 / 256, 256, 0, stream>>>(emb, x, E16);
  bsum_kernel<<<16, 256, 0, stream>>>(b_ih, b_hh, bs, G4);
  h0_kernel<<<128, 256, 0, stream>>>(z, W_h, b_h, h0f);

  dim3 g1(G4 / 128, BT / 128);     // 32 x 32
  gemmxg_kernel<<<g1, 256, 0, stream>>>(E16, Wih16, bs, XG2, BT, G4, DE);

  fused_kernel<<<256, 512, 0, stream>>>(Whh16, XG2, h0f, HS, Wout16, b_out, out,
                                        bar, cnt, gready);
}

// Round 18
// 805.955 us; speedup vs baseline: 1.8165x; 1.0522x over previous
//
#include <hip/hip_runtime.h>

typedef _Float16 f16;
typedef _Float16 f16x8 __attribute__((ext_vector_type(8)));
typedef _Float16 f16x4 __attribute__((ext_vector_type(4)));
typedef float    f32x4 __attribute__((ext_vector_type(4)));
typedef unsigned long long ull;

static constexpr int Bb  = 32;
static constexpr int Tt  = 128;
static constexpr int HID = 1024;
static constexpr int ZD  = 256;
static constexpr int DE  = 512;
static constexpr int VOC = 32000;
static constexpr int BT  = Bb * Tt;   // 4096
static constexpr int G4  = 4 * HID;   // 4096
static constexpr int NLSTM = 64;      // lstm-role blocks (16 hidden units each)
static constexpr int NCOL  = 125;     // worker columns (256-wide output panels)
// HS layout is T-MAJOR: row m' = t*32 + b. Writes are agent-scope; all reads are
// flag-gated after the writes, so normal cached loads are coherent.
// Workers: STATIC ng-ownership (block 64+ng owns column panel ng, iterates mg
// 0..15 in order) -> Wout panel fetched from HBM once per worker (64 MB total),
// L2-resident across its 16 mg-iterations; natural pacing behind the recurrence.

// ---- async global->LDS, 16B per lane; LDS dest = wave-uniform base + lane*16 ----
__device__ __forceinline__ void gld_lds16(const void* g, void* l) {
  __builtin_amdgcn_global_load_lds((const __attribute__((address_space(1))) unsigned int*)g,
                                   (__attribute__((address_space(3))) unsigned int*)l,
                                   16, 0, 0);
}

// ---------------- f32 -> f16 convert (vectorized) ----------------
__global__ void cvt_kernel(const float* __restrict__ s, f16* __restrict__ d, int n4) {
  int i = blockIdx.x * blockDim.x + threadIdx.x;
  int st = gridDim.x * blockDim.x;
  for (; i < n4; i += st) {
    float4 v = ((const float4*)s)[i];
    f16x4 o = { (f16)v.x, (f16)v.y, (f16)v.z, (f16)v.w };
    ((f16x4*)d)[i] = o;
  }
}

// ---------------- embedding gather -> f16 ----------------
__global__ void gather_kernel(const float* __restrict__ emb, const int* __restrict__ x,
                              f16* __restrict__ E) {
  int g = blockIdx.x * 256 + threadIdx.x;   // BT*DE/8 threads
  int m = g >> 6, seg = (g & 63) * 8;
  int idx = x[m];
  const float* src = emb + (size_t)idx * DE + seg;
  float4 a = *(const float4*)src;
  float4 b = *(const float4*)(src + 4);
  f16x8 o = { (f16)a.x,(f16)a.y,(f16)a.z,(f16)a.w,(f16)b.x,(f16)b.y,(f16)b.z,(f16)b.w };
  *(f16x8*)(E + (size_t)m * DE + seg) = o;
}

// ---------------- bias sum ----------------
__global__ void bsum_kernel(const float* __restrict__ a, const float* __restrict__ b,
                            float* __restrict__ o, int n) {
  int i = blockIdx.x * blockDim.x + threadIdx.x;
  if (i < n) o[i] = a[i] + b[i];
}

// ---------------- h0 = tanh(z @ W_h^T + b_h), store f16 ----------------
__global__ __launch_bounds__(256) void h0_kernel(const float* __restrict__ z,
                                                 const float* __restrict__ W_h,
                                                 const float* __restrict__ b_h,
                                                 f16* __restrict__ h0f) {
  __shared__ float zs[32][260];
  __shared__ float wsl[8][260];
  const int jc = blockIdx.x, tid = threadIdx.x;
  #pragma unroll
  for (int it = 0; it < 8; ++it) {
    int idx = it * 256 + tid;
    float4 v = ((const float4*)z)[idx];
    int b = idx >> 6, k = (idx & 63) * 4;
    zs[b][k] = v.x; zs[b][k+1] = v.y; zs[b][k+2] = v.z; zs[b][k+3] = v.w;
  }
  #pragma unroll
  for (int it = 0; it < 2; ++it) {
    int idx = it * 256 + tid;
    float4 v = ((const float4*)(W_h + (size_t)jc * 8 * ZD))[idx];
    int r = idx >> 6, k = (idx & 63) * 4;
    wsl[r][k] = v.x; wsl[r][k+1] = v.y; wsl[r][k+2] = v.z; wsl[r][k+3] = v.w;
  }
  __syncthreads();
  const int b = tid >> 3, jj = tid & 7;
  const int j = jc * 8 + jj;
  float acc = b_h[j];
  for (int k = 0; k < ZD; ++k) acc += zs[b][k] * wsl[jj][k];
  h0f[(size_t)b * HID + j] = (f16)tanhf(acc);
}

// ---------------- GEMM 128x128 (proven): C = A @ B^T + bias, XG output layout ---
__global__ __launch_bounds__(256, 2) void gemmxg_kernel(
    const f16* __restrict__ A, const f16* __restrict__ B,
    const float* __restrict__ bias, float* __restrict__ C,
    int M, int N, int K) {
  __shared__ f16 As[128 * 64];
  __shared__ f16 Bs[128 * 64];
  const int n0 = blockIdx.x * 128, m0 = blockIdx.y * 128;
  const int tid = threadIdx.x, wid = tid >> 6, lane = tid & 63;
  const int wm = wid >> 1, wn = wid & 1;
  const int sr = lane >> 3, sk = (lane & 7) * 8;
  f32x4 acc[4][4] = {};
  for (int k0 = 0; k0 < K; k0 += 64) {
    __syncthreads();
    #pragma unroll
    for (int i = 0; i < 4; ++i) {
      int rr = (wid * 4 + i) * 8;
      gld_lds16(A + (size_t)(m0 + rr + sr) * K + k0 + sk, &As[rr * 64]);
      gld_lds16(B + (size_t)(n0 + rr + sr) * K + k0 + sk, &Bs[rr * 64]);
    }
    __syncthreads();
    #pragma unroll
    for (int ks = 0; ks < 2; ++ks) {
      f16x8 af[4], bf[4];
      #pragma unroll
      for (int mt = 0; mt < 4; ++mt)
        af[mt] = *(const f16x8*)&As[(wm * 64 + mt * 16 + (lane & 15)) * 64 + ks * 32 + (lane >> 4) * 8];
      #pragma unroll
      for (int nt = 0; nt < 4; ++nt)
        bf[nt] = *(const f16x8*)&Bs[(wn * 64 + nt * 16 + (lane & 15)) * 64 + ks * 32 + (lane >> 4) * 8];
      #pragma unroll
      for (int mt = 0; mt < 4; ++mt)
        #pragma unroll
        for (int nt = 0; nt < 4; ++nt)
          acc[mt][nt] = __builtin_amdgcn_mfma_f32_16x16x32_f16(af[mt], bf[nt], acc[mt][nt], 0, 0, 0);
    }
  }
  #pragma unroll
  for (int nt = 0; nt < 4; ++nt) {
    int col = n0 + wn * 64 + nt * 16 + (lane & 15);
    float bv = bias[col];
    #pragma unroll
    for (int mt = 0; mt < 4; ++mt) {
      int row = m0 + wm * 64 + mt * 16 + (lane >> 4) * 4;
      int b = row >> 7, t0 = row & 127;
      float4 v = { acc[mt][nt][0] + bv, acc[mt][nt][1] + bv,
                   acc[mt][nt][2] + bv, acc[mt][nt][3] + bv };
      *(float4*)&C[((size_t)col * 32 + b) * 128 + t0] = v;
    }
  }
}

// =================================================================================
// FUSED persistent kernel: 256 blocks x 512 threads, 1 block/CU (capacity-resident).
//   blocks 0..63   : LSTM recurrence role (t-major HS), then exit.
//   blocks 64..188 : GEMM workers, STATIC ng-ownership (ng = bid-64), mg 0..15.
//   blocks 189..255: exit immediately.
// =================================================================================
static constexpr int SM_HL   = 0;                       // f16 hl[32][1032] = 66048 B
static constexpr int SM_PART = 66048;                   // float part[8][64][33] = 67584 B
static constexpr int SM_FL   = 133632;                  // unsigned fl[64] mirror = 256 B
static constexpr int SM_SIZE = 133904;

__device__ void lstm_role(const f16* __restrict__ Whh16, const float* __restrict__ XG2,
                          const f16* __restrict__ h0f, f16* __restrict__ HS,
                          unsigned* __restrict__ bar, unsigned* __restrict__ gready,
                          char* smem) {
  const int bid = blockIdx.x, tid = threadIdx.x;
  const int lane = tid & 63, wid = tid >> 6;
  const int lr = lane & 15, hi = lane >> 4;
  const int j0 = bid * 16;
  f16 (*hl)[1032] = (f16 (*)[1032])(smem + SM_HL);
  float (*part)[64][33] = (float (*)[64][33])(smem + SM_PART);
  unsigned* fl = (unsigned*)(smem + SM_FL);

  if (tid < 64) fl[tid] = 0;

  f16x8 wfrag[4][4];
  #pragma unroll
  for (int rt = 0; rt < 4; ++rt) {
    int g = rt * HID + j0 + lr;
    #pragma unroll
    for (int kk = 0; kk < 4; ++kk)
      wfrag[rt][kk] = *(const f16x8*)(Whh16 + (size_t)g * HID + wid * 128 + kk * 32 + hi * 8);
  }

  const int ub = tid & 15, bb = tid >> 4;
  float creg = 0.f;
  __syncthreads();   // fl init visible

  for (int t = 0; t < Tt; ++t) {
    float xg[4];
    #pragma unroll
    for (int q = 0; q < 4; ++q)
      xg[q] = XG2[((size_t)(q * HID + j0 + ub) * 32 + bb) * 128 + t];

    // ---- per-wave readiness: wave 0 polls bar + mirrors to LDS; waves 1..7
    //      spin on the LDS mirror for THEIR 8 producers only ----
    if (t > 0) {
      if (wid == 0) {
        for (;;) {
          unsigned f = __hip_atomic_load(&bar[lane], __ATOMIC_RELAXED, __HIP_MEMORY_SCOPE_AGENT);
          __hip_atomic_store(&fl[lane], f, __ATOMIC_RELAXED, __HIP_MEMORY_SCOPE_WORKGROUP);
          if (__all(f >= (unsigned)t)) break;
        }
        if (bid == 0 && lane == 0)
          __hip_atomic_store(gready, (unsigned)t, __ATOMIC_RELAXED, __HIP_MEMORY_SCOPE_AGENT);
      } else {
        const int p = wid * 8 + (lane & 7);
        for (;;) {
          unsigned f = __hip_atomic_load(&fl[p], __ATOMIC_RELAXED, __HIP_MEMORY_SCOPE_WORKGROUP);
          if (__all(f >= (unsigned)t)) break;
        }
      }
    }

    // ---- stage own k-slice: wave wid loads ALL 32 batch rows x units
    //      [wid*128, wid*128+128) -- wave-private, no barrier needed ----
    {
      const int uo = wid * 128 + (lane & 31) * 4;   // ull = 4 units
      #pragma unroll
      for (int ps = 0; ps < 16; ++ps) {
        int row = ps * 2 + (lane >> 5);
        const f16* hb = (t == 0) ? (h0f + (size_t)row * HID)
                                 : (HS + (size_t)((t - 1) * 32 + row) * HID);
        ull v = *(const ull*)(hb + uo);
        *(ull*)&hl[row][uo] = v;
      }
    }

    // ---- gate MFMA: C[64 gate rows][32 batches], this wave's k-eighth ----
    {
      f32x4 acc[4][2] = {};
      #pragma unroll
      for (int kk = 0; kk < 4; ++kk) {
        int ko = wid * 128 + kk * 32 + hi * 8;
        f16x8 bf0 = *(const f16x8*)&hl[lr][ko];
        f16x8 bf1 = *(const f16x8*)&hl[16 + lr][ko];
        #pragma unroll
        for (int rt = 0; rt < 4; ++rt) {
          acc[rt][0] = __builtin_amdgcn_mfma_f32_16x16x32_f16(wfrag[rt][kk], bf0, acc[rt][0], 0, 0, 0);
          acc[rt][1] = __builtin_amdgcn_mfma_f32_16x16x32_f16(wfrag[rt][kk], bf1, acc[rt][1], 0, 0, 0);
        }
      }
      #pragma unroll
      for (int rt = 0; rt < 4; ++rt)
        #pragma unroll
        for (int bt = 0; bt < 2; ++bt)
          #pragma unroll
          for (int p = 0; p < 4; ++p)
            part[wid][rt * 16 + hi * 4 + p][bt * 16 + lr] = acc[rt][bt][p];
    }
    __syncthreads();   // S1: part complete (and all waves past their hl reads)

    // ---- LSTM update: thread (ub, bb); h store agent-coherent 2B, t-major ----
    {
      float g4[4];
      #pragma unroll
      for (int q = 0; q < 4; ++q) {
        int i = q * 16 + ub;
        float s = xg[q];
        #pragma unroll
        for (int w = 0; w < 8; ++w) s += part[w][i][bb];
        g4[q] = s;
      }
      float ig = 1.f / (1.f + __expf(-g4[0]));
      float fg = 1.f / (1.f + __expf(-g4[1]));
      float gg = tanhf(g4[2]);
      float og = 1.f / (1.f + __expf(-g4[3]));
      creg = fg * creg + ig * gg;
      float h = og * tanhf(creg);
      union { f16 h; unsigned short u; } cv;
      cv.h = (f16)h;
      __hip_atomic_store((unsigned short*)&HS[(size_t)(t * 32 + bb) * HID + j0 + ub],
                         cv.u, __ATOMIC_RELAXED, __HIP_MEMORY_SCOPE_AGENT);
    }

    // ---- drain + flag (every t; workers need t=127 too) ----
    asm volatile("s_waitcnt vmcnt(0)" ::: "memory");
    __syncthreads();   // S2: all h stores at IF
    if (tid == 0)
      __hip_atomic_store(&bar[bid], (unsigned)(t + 1),
                         __ATOMIC_RELAXED, __HIP_MEMORY_SCOPE_AGENT);
  }

  // block 0: final aggregation (flags reach 128 only after all finish t=127)
  if (bid == 0) {
    if (wid == 0) {
      for (;;) {
        unsigned f = __hip_atomic_load(&bar[lane], __ATOMIC_RELAXED, __HIP_MEMORY_SCOPE_AGENT);
        if (__all(f >= (unsigned)Tt)) break;
      }
      if (lane == 0)
        __hip_atomic_store(gready, (unsigned)Tt, __ATOMIC_RELAXED, __HIP_MEMORY_SCOPE_AGENT);
    }
    __syncthreads();
  }
}

__device__ void worker_role(const f16* __restrict__ HS, const f16* __restrict__ Wout16,
                            const float* __restrict__ b_out, float* __restrict__ out,
                            unsigned* __restrict__ gready, char* smem) {
  const int ng = blockIdx.x - NLSTM;           // static column ownership
  const int tid = threadIdx.x, wid = tid >> 6, lane = tid & 63;
  const int wm = wid >> 2, wn = wid & 3;
  const int lr = lane & 15, hi = lane >> 4;
  const int srow = lane >> 2;
  const int scol = ((lane & 3) ^ ((lane >> 3) & 3)) * 8;   // pre-swizzled source col
  const int sx   = (hi ^ ((lr >> 1) & 3)) * 8;             // swizzled read slot
  f16* As = (f16*)(smem);            // [4][8192] halves = 65536 B
  f16* Bs = (f16*)(smem + 65536);    // [4][8192]
  const int cb0 = wid * 2, cb1 = wid * 2 + 1;
  const int n0 = ng * 256;

  for (int mg = 0; mg < 16; ++mg) {
    // readiness: all lstm blocks completed step 8*mg+7 (gready >= 8mg+8)
    if (wid == 0) {
      const unsigned tgt = (unsigned)(8 * mg + 8);
      for (;;) {
        unsigned g = __hip_atomic_load(gready, __ATOMIC_RELAXED, __HIP_MEMORY_SCOPE_AGENT);
        if (g >= tgt) break;
        __builtin_amdgcn_s_sleep(64);
      }
    }
    __syncthreads();

    const int m0 = mg * 256;
    f32x4 acc[8][4] = {};

    auto STAGE = [&](int kt) {
      const int k0 = kt << 5, buf = kt & 3;
      gld_lds16(HS     + (size_t)(m0 + cb0 * 16 + srow) * HID + k0 + scol, As + buf * 8192 + cb0 * 512);
      gld_lds16(Wout16 + (size_t)(n0 + cb0 * 16 + srow) * HID + k0 + scol, Bs + buf * 8192 + cb0 * 512);
      gld_lds16(HS     + (size_t)(m0 + cb1 * 16 + srow) * HID + k0 + scol, As + buf * 8192 + cb1 * 512);
      gld_lds16(Wout16 + (size_t)(n0 + cb1 * 16 + srow) * HID + k0 + scol, Bs + buf * 8192 + cb1 * 512);
    };

    STAGE(0); STAGE(1); STAGE(2);
    for (int kt = 0; kt < 32; ++kt) {
      if (kt < 30)       asm volatile("s_waitcnt vmcnt(8)" ::: "memory");
      else if (kt == 30) asm volatile("s_waitcnt vmcnt(4)" ::: "memory");
      else               asm volatile("s_waitcnt vmcnt(0)" ::: "memory");
      __builtin_amdgcn_s_barrier();
      if (kt + 3 < 32) STAGE(kt + 3);
      const f16* as = As + (kt & 3) * 8192;
      const f16* bs = Bs + (kt & 3) * 8192;
      f16x8 af[8], bf[4];
      #pragma unroll
      for (int mt = 0; mt < 8; ++mt)
        af[mt] = *(const f16x8*)&as[(wm * 128 + mt * 16 + lr) * 32 + sx];
      #pragma unroll
      for (int nt = 0; nt < 4; ++nt)
        bf[nt] = *(const f16x8*)&bs[(wn * 64 + nt * 16 + lr) * 32 + sx];
      __builtin_amdgcn_s_setprio(1);
      #pragma unroll
      for (int mt = 0; mt < 8; ++mt)
        #pragma unroll
        for (int nt = 0; nt < 4; ++nt)
          acc[mt][nt] = __builtin_amdgcn_mfma_f32_16x16x32_f16(af[mt], bf[nt], acc[mt][nt], 0, 0, 0);
      __builtin_amdgcn_s_setprio(0);
    }

    // epilogue: un-permute rows (m' = t*32+b -> out row b*128+t), add bias,
    // NON-TEMPORAL stores (out is write-once; keep it out of the caches)
    #pragma unroll
    for (int nt = 0; nt < 4; ++nt) {
      int col = n0 + wn * 64 + nt * 16 + lr;
      float bv = b_out[col];
      #pragma unroll
      for (int mt = 0; mt < 8; ++mt) {
        int mbase = m0 + wm * 128 + mt * 16 + hi * 4;
        #pragma unroll
        for (int p = 0; p < 4; ++p) {
          int mp = mbase + p;
          int orow = (mp & 31) * 128 + (mp >> 5);
          __builtin_nontemporal_store(acc[mt][nt][p] + bv,
                                      &out[(size_t)orow * VOC + col]);
        }
      }
    }
    __syncthreads();   // all frag reads done before next tile's STAGE overwrites LDS
  }
}

__global__ __launch_bounds__(512, 1) void fused_kernel(
    const f16* __restrict__ Whh16, const float* __restrict__ XG2,
    const f16* __restrict__ h0f, f16* __restrict__ HS,
    const f16* __restrict__ Wout16, const float* __restrict__ b_out,
    float* __restrict__ out, unsigned* __restrict__ bar,
    unsigned* __restrict__ gready) {
  __shared__ __align__(16) char smem[SM_SIZE];
  if (blockIdx.x < NLSTM) {
    lstm_role(Whh16, XG2, h0f, HS, bar, gready, smem);
  } else if (blockIdx.x < NLSTM + NCOL) {
    worker_role(HS, Wout16, b_out, out, gready, smem);
  }
}

extern "C" void kernel_launch(void* const* d_in, const int* in_sizes, int n_in,
                              void* d_out, int out_size, void* d_ws, size_t ws_size,
                              hipStream_t stream) {
  const float* z     = (const float*)d_in[0];
  const int*   x     = (const int*)d_in[1];
  const float* W_h   = (const float*)d_in[2];
  const float* b_h   = (const float*)d_in[3];
  const float* emb   = (const float*)d_in[4];
  const float* W_ih  = (const float*)d_in[5];
  const float* W_hh  = (const float*)d_in[6];
  const float* b_ih  = (const float*)d_in[7];
  const float* b_hh  = (const float*)d_in[8];
  const float* W_out = (const float*)d_in[9];
  const float* b_out = (const float*)d_in[10];
  float* out = (float*)d_out;

  char* ws = (char*)d_ws;
  size_t off = 0;
  auto carve = [&](size_t n) { char* p = ws + off; off += (n + 255) & ~(size_t)255; return p; };
  f16*   E16    = (f16*)carve((size_t)BT * DE * 2);     // 4 MB
  f16*   Wih16  = (f16*)carve((size_t)G4 * DE * 2);     // 4 MB
  f16*   Whh16  = (f16*)carve((size_t)G4 * HID * 2);    // 8 MB
  f16*   Wout16 = (f16*)carve((size_t)VOC * HID * 2);   // 64 MB
  float* XG2    = (float*)carve((size_t)BT * G4 * 4);   // 64 MB, [g][b][t]
  f16*   HS     = (f16*)carve((size_t)BT * HID * 2);    // 8 MB, t-major rows
  f16*   h0f    = (f16*)carve((size_t)Bb * HID * 2);
  float* bs     = (float*)carve((size_t)G4 * 4);
  unsigned* bar    = (unsigned*)carve(256);
  unsigned* gready = (unsigned*)carve(256);

  (void)hipMemsetAsync(bar, 0, 512, stream);   // bar + gready (contiguous)

  cvt_kernel<<<2048, 256, 0, stream>>>(W_ih,  Wih16,  G4 * DE / 4);
  cvt_kernel<<<2048, 256, 0, stream>>>(W_hh,  Whh16,  G4 * HID / 4);
  cvt_kernel<<<2048, 256, 0, stream>>>(W_out, Wout16, VOC * HID / 4);
  gather_kernel<<<BT * DE / 8 / 256, 256, 0, stream>>>(emb, x, E16);
  bsum_kernel<<<16, 256, 0, stream>>>(b_ih, b_hh, bs, G4);
  h0_kernel<<<128, 256, 0, stream>>>(z, W_h, b_h, h0f);

  dim3 g1(G4 / 128, BT / 128);     // 32 x 32
  gemmxg_kernel<<<g1, 256, 0, stream>>>(E16, Wih16, bs, XG2, BT, G4, DE);

  fused_kernel<<<256, 512, 0, stream>>>(Whh16, XG2, h0f, HS, Wout16, b_out, out,
                                        bar, gready);
}